// Round 5
// baseline (614.683 us; speedup 1.0000x reference)
//
#include <hip/hip_runtime.h>
#include <hip/hip_bf16.h>

typedef short bf16x8 __attribute__((ext_vector_type(8)));
typedef _Float16 f16;
typedef f16 f16x8 __attribute__((ext_vector_type(8)));
typedef float f32x4 __attribute__((ext_vector_type(4)));
typedef unsigned short u16;
typedef u16 u16x8 __attribute__((ext_vector_type(8)));
typedef unsigned int u32;
typedef u32 u32x2 __attribute__((ext_vector_type(2)));

#define B_  2
#define L_  4096
#define F_  512
#define H_  8
#define D_  64
#define M_  8192       // B_*L_
#define NSPL 4         // flash split-K factor (R5: 2->4 for 4 blocks/CU)
#define KQ  (L_ / NSPL)

#define LOG2E 1.442695041f

__device__ inline u16 f2bf(float f) {
    union { float f; unsigned u; } v; v.f = f;
    unsigned r = v.u + 0x7fff + ((v.u >> 16) & 1);  // RNE
    return (u16)(r >> 16);
}
__device__ inline u16 f2h(float f) {
    union { f16 h; u16 u; } v; v.h = (f16)f;  // RNE hw cvt
    return v.u;
}
__device__ inline float h2f(u16 u) {
    union { u16 u; f16 h; } v; v.u = u;
    return (float)v.h;
}

// ---------------------------------------------------------------------------
// Fused weight transpose: W [512 k][512 n] fp32 -> Wt [512 n][512 k] fp16.
// ---------------------------------------------------------------------------
__global__ __launch_bounds__(256) void wt_kernel(
    const float* __restrict__ Wq, const float* __restrict__ Wk,
    const float* __restrict__ Wv, const float* __restrict__ Wo,
    u16* __restrict__ Tq, u16* __restrict__ Tk,
    u16* __restrict__ Tv, u16* __restrict__ To) {
    __shared__ float t[32][33];
    const int z = blockIdx.z;
    const float* in = (z == 0) ? Wq : (z == 1) ? Wk : (z == 2) ? Wv : Wo;
    u16* out = (z == 0) ? Tq : (z == 1) ? Tk : (z == 2) ? Tv : To;
    int k0 = blockIdx.y * 32, n0 = blockIdx.x * 32;
    int c = threadIdx.x & 31, r8 = threadIdx.x >> 5;
#pragma unroll
    for (int i = 0; i < 4; ++i) {
        int r = r8 * 4 + i;
        t[r][c] = in[(size_t)(k0 + r) * F_ + n0 + c];
    }
    __syncthreads();
#pragma unroll
    for (int i = 0; i < 4; ++i) {
        int r = r8 * 4 + i;
        out[(size_t)(n0 + r) * F_ + k0 + c] = f2h(t[c][r]);
    }
}

// ---------------------------------------------------------------------------
// Fused projection kernel, 128x64 tile, register prefetch (loads issued
// AFTER the barrier pair so no barrier drains a fresh vmcnt).
// z=0: Q = Xq*Wq (scaled log2e) -> [B,H,L,D] fp16.
// z=1: K -> [B,H,L,D] fp16;  V -> [B,H,D,L] bf16 transposed.
// ---------------------------------------------------------------------------
__global__ __launch_bounds__(256, 3) void proj_kernel(
    const float* __restrict__ Xq, const float* __restrict__ Xkv,
    const u16* __restrict__ Wqt, const u16* __restrict__ Wkt,
    const u16* __restrict__ Wvt,
    u16* __restrict__ Qw, u16* __restrict__ Kw, u16* __restrict__ Vw) {
    __shared__ u16 Ah[128][72];
    __shared__ u16 B1[64][72];
    __shared__ u16 B2[64][72];
    const int tid = threadIdx.x;
    const int w = tid >> 6, lane = tid & 63, lx = lane & 15, quad = lane >> 4;
    const int m0 = blockIdx.y * 128, n0 = blockIdx.x * 64;
    const bool isKV = (blockIdx.z == 1);
    const float* A = isKV ? Xkv : Xq;
    const u16* W1 = isKV ? Wkt : Wqt;

    float4 apre[8];
    u16x8 b1p[2], b2p[2];

    auto load_ab = [&](int k0) {
#pragma unroll
        for (int it = 0; it < 4; ++it) {
            int slot = tid + it * 256, r = slot >> 3, g = (slot & 7) * 8;
            apre[2 * it]     = *(const float4*)(A + (size_t)(m0 + r) * F_ + k0 + g);
            apre[2 * it + 1] = *(const float4*)(A + (size_t)(m0 + r) * F_ + k0 + g + 4);
        }
#pragma unroll
        for (int it = 0; it < 2; ++it) {
            int slot = tid + it * 256, r = slot >> 3, g = (slot & 7) * 8;
            b1p[it] = *(const u16x8*)(W1 + (size_t)(n0 + r) * F_ + k0 + g);
            if (isKV)
                b2p[it] = *(const u16x8*)(Wvt + (size_t)(n0 + r) * F_ + k0 + g);
        }
    };
    auto write_ab = [&]() {
#pragma unroll
        for (int it = 0; it < 4; ++it) {
            int slot = tid + it * 256, r = slot >> 3, g = (slot & 7) * 8;
            float4 f0 = apre[2 * it], f1 = apre[2 * it + 1];
            u16 th[8] = {f2h(f0.x), f2h(f0.y), f2h(f0.z), f2h(f0.w),
                         f2h(f1.x), f2h(f1.y), f2h(f1.z), f2h(f1.w)};
            *(u16x8*)&Ah[r][g] = *(u16x8*)th;
        }
#pragma unroll
        for (int it = 0; it < 2; ++it) {
            int slot = tid + it * 256, r = slot >> 3, g = (slot & 7) * 8;
            *(u16x8*)&B1[r][g] = b1p[it];
            if (isKV) *(u16x8*)&B2[r][g] = b2p[it];
        }
    };

    f32x4 acc1[2][4] = {}, acc2[2][4] = {};

    load_ab(0);
    write_ab();
    __syncthreads();
    load_ab(64);   // in flight during first compute

    for (int k0 = 0; k0 < F_; k0 += 64) {
#pragma unroll
        for (int ks = 0; ks < 2; ++ks) {
            f16x8 af[2];
#pragma unroll
            for (int mf = 0; mf < 2; ++mf)
                af[mf] = *(const f16x8*)&Ah[w * 32 + mf * 16 + lx][ks * 32 + quad * 8];
#pragma unroll
            for (int nt = 0; nt < 4; ++nt) {
                f16x8 b1 = *(const f16x8*)&B1[nt * 16 + lx][ks * 32 + quad * 8];
#pragma unroll
                for (int mf = 0; mf < 2; ++mf)
                    acc1[mf][nt] = __builtin_amdgcn_mfma_f32_16x16x32_f16(af[mf], b1, acc1[mf][nt], 0, 0, 0);
                if (isKV) {
                    f16x8 b2 = *(const f16x8*)&B2[nt * 16 + lx][ks * 32 + quad * 8];
#pragma unroll
                    for (int mf = 0; mf < 2; ++mf)
                        acc2[mf][nt] = __builtin_amdgcn_mfma_f32_16x16x32_f16(af[mf], b2, acc2[mf][nt], 0, 0, 0);
                }
            }
        }
        if (k0 < F_ - 64) {
            __syncthreads();   // loads for k0+64 landed during this compute
            write_ab();
            __syncthreads();
            if (k0 < F_ - 128) load_ab(k0 + 128);  // issued AFTER barriers
        }
    }

    const int h = n0 >> 6;
    const float scl = isKV ? 1.0f : LOG2E;
    u16* C1 = isKV ? Kw : Qw;
#pragma unroll
    for (int mf = 0; mf < 2; ++mf)
#pragma unroll
        for (int nt = 0; nt < 4; ++nt)
#pragma unroll
            for (int i = 0; i < 4; ++i) {
                int m = m0 + w * 32 + mf * 16 + quad * 4 + i;
                int b = m >> 12, l = m & 4095;
                int d = nt * 16 + lx;
                C1[((size_t)(b * H_ + h) * L_ + l) * D_ + d] = f2h(acc1[mf][nt][i] * scl);
            }
    if (isKV) {
        __syncthreads();
#pragma unroll
        for (int mf = 0; mf < 2; ++mf)
#pragma unroll
            for (int nt = 0; nt < 4; ++nt)
#pragma unroll
                for (int i = 0; i < 4; ++i)
                    Ah[w * 32 + mf * 16 + quad * 4 + i][nt * 16 + lx] = f2bf(acc2[mf][nt][i]);
        __syncthreads();
        int d = tid >> 2, seg = (tid & 3) * 32;
        int b = m0 >> 12;
        u16 tmp[32];
#pragma unroll
        for (int j = 0; j < 32; ++j) tmp[j] = Ah[seg + j][d];
        size_t base = ((size_t)(b * H_ + h) * D_ + d) * L_ + (m0 & 4095) + seg;
#pragma unroll
        for (int c = 0; c < 4; ++c)
            *(u16x8*)(Vw + base + c * 8) = *(u16x8*)&tmp[c * 8];
    }
}

// ---------------------------------------------------------------------------
// Out-projection GEMM, 128x64 tile: A fp16 x Wt fp16 -> C fp32.
// (R4 lesson: fusing the split-K combine here recomputes it per n0-tile
// (8x) and doubles A traffic — net −11 µs. Keep reduce separate.)
// ---------------------------------------------------------------------------
__global__ __launch_bounds__(256) void out_gemm(const u16* __restrict__ A16,
                                                const u16* __restrict__ Wt,
                                                float* __restrict__ Cf) {
    __shared__ u16 As[128][72];
    __shared__ u16 Bs[64][72];
    const int tid = threadIdx.x;
    const int w = tid >> 6, lane = tid & 63, lx = lane & 15, quad = lane >> 4;
    const int m0 = blockIdx.y * 128, n0 = blockIdx.x * 64;

    u16x8 a16p[4];
    u16x8 bp[2];

    auto load_ab = [&](int k0) {
#pragma unroll
        for (int it = 0; it < 4; ++it) {
            int slot = tid + it * 256, r = slot >> 3, g = (slot & 7) * 8;
            a16p[it] = *(const u16x8*)(A16 + (size_t)(m0 + r) * F_ + k0 + g);
        }
#pragma unroll
        for (int it = 0; it < 2; ++it) {
            int slot = tid + it * 256, r = slot >> 3, g = (slot & 7) * 8;
            bp[it] = *(const u16x8*)(Wt + (size_t)(n0 + r) * F_ + k0 + g);
        }
    };
    auto write_ab = [&]() {
#pragma unroll
        for (int it = 0; it < 4; ++it) {
            int slot = tid + it * 256, r = slot >> 3, g = (slot & 7) * 8;
            *(u16x8*)&As[r][g] = a16p[it];
        }
#pragma unroll
        for (int it = 0; it < 2; ++it) {
            int slot = tid + it * 256, r = slot >> 3, g = (slot & 7) * 8;
            *(u16x8*)&Bs[r][g] = bp[it];
        }
    };

    f32x4 acc[2][4] = {};

    load_ab(0);
    write_ab();
    __syncthreads();
    load_ab(64);

    for (int k0 = 0; k0 < F_; k0 += 64) {
#pragma unroll
        for (int ks = 0; ks < 2; ++ks) {
            f16x8 af[2];
#pragma unroll
            for (int mf = 0; mf < 2; ++mf)
                af[mf] = *(const f16x8*)&As[w * 32 + mf * 16 + lx][ks * 32 + quad * 8];
#pragma unroll
            for (int nt = 0; nt < 4; ++nt) {
                f16x8 bf = *(const f16x8*)&Bs[nt * 16 + lx][ks * 32 + quad * 8];
#pragma unroll
                for (int mf = 0; mf < 2; ++mf)
                    acc[mf][nt] = __builtin_amdgcn_mfma_f32_16x16x32_f16(af[mf], bf, acc[mf][nt], 0, 0, 0);
            }
        }
        if (k0 < F_ - 64) {
            __syncthreads();
            write_ab();
            __syncthreads();
            if (k0 < F_ - 128) load_ab(k0 + 128);
        }
    }

#pragma unroll
    for (int mf = 0; mf < 2; ++mf)
#pragma unroll
        for (int nt = 0; nt < 4; ++nt)
#pragma unroll
            for (int i = 0; i < 4; ++i) {
                int m = m0 + w * 32 + mf * 16 + quad * 4 + i;
                int n = n0 + nt * 16 + lx;
                Cf[(size_t)m * F_ + n] = acc[mf][nt][i];
            }
}

// ---------------------------------------------------------------------------
// MFMA flash attention, R5: R2 structure with NSPL=4 (split-K x4).
// Why: R2/R4 counters (MfmaUtil 39, VALUBusy 45, Occupancy 17%) showed
// latency-bound at 2 waves/SIMD — the QK->softmax->PV chain is serial per
// wave and the per-kt barrier phase-locks waves, so the matrix pipe idles
// during softmax. Footprint (96 VGPR, 36.9 KB LDS) fits 4 blocks/CU:
// NSPL=4 -> grid 1024 -> 4 waves/SIMD, work-conserved per-CU demand,
// double the TLP to fill the softmax gaps. launch_bounds(256,4) caps
// VGPR at 128 >= current 96 (no regalloc squeeze expected).
// BQ=256 (4 waves x 64q, qf=4), Q in regs, P in regs (permlane swap),
// K/V in LDS double-buffer, ONE barrier per kt.
// XCD swizzle: (x&7) -> 2 heads per XCD.
// ---------------------------------------------------------------------------
__global__ __launch_bounds__(256, 4) void flash_mfma(
    const u16* __restrict__ Qg, const u16* __restrict__ Kg,
    const u16* __restrict__ Vtg, u16* __restrict__ On, float* __restrict__ Ls) {
    __shared__ u16 Ks[2][64][72];   // fp16, double-buffered
    __shared__ u16 Vs[2][64][72];   // bf16, V^T tile [d][kcol], double-buffered

    const int tid = threadIdx.x;
    const int w = tid >> 6, lane = tid & 63, lx = lane & 15, quad = lane >> 4;

    // decode: 1024 = 8 xcd * (2 head * 4 split * 16 qtile)
    const int x = blockIdx.x;
    const int t = x >> 3;              // 0..127 within xcd
    const int hh = t >> 6;             // 0..1
    const int s = (t >> 4) & 3;        // 0..3 split
    const int bh = (x & 7) * 2 + hh;
    const int q0 = (t & 15) * 256;

    const u16* Qp = Qg + ((size_t)bh * L_ + q0) * D_;
    const u16* Kp = Kg + (size_t)bh * L_ * D_ + (size_t)(s * KQ) * D_;
    const u16* Vp = Vtg + (size_t)bh * D_ * L_ + s * KQ;

    // Q fragments straight to registers (B-operand layout), 64 q-rows/wave
    f16x8 qreg[4][2];
#pragma unroll
    for (int qf = 0; qf < 4; ++qf)
#pragma unroll
        for (int ks = 0; ks < 2; ++ks)
            qreg[qf][ks] = *(const f16x8*)(Qp + (size_t)(w * 64 + qf * 16 + lx) * D_ +
                                           ks * 32 + quad * 8);

    u16x8 kp[2], vp[2];
    auto load_kv = [&](int kt) {
#pragma unroll
        for (int it = 0; it < 2; ++it) {
            int slot = tid + it * 256, r = slot >> 3, g = (slot & 7) * 8;
            kp[it] = *(const u16x8*)(Kp + (size_t)(kt * 64 + r) * D_ + g);
            vp[it] = *(const u16x8*)(Vp + (size_t)r * L_ + kt * 64 + g);
        }
    };
    auto write_kv = [&](int p) {
#pragma unroll
        for (int it = 0; it < 2; ++it) {
            int slot = tid + it * 256, r = slot >> 3, g = (slot & 7) * 8;
            *(u16x8*)&Ks[p][r][g] = kp[it];
            *(u16x8*)&Vs[p][r][g] = vp[it];
        }
    };

    const bf16x8 vone = {0x3F80, 0x3F80, 0x3F80, 0x3F80,
                         0x3F80, 0x3F80, 0x3F80, 0x3F80};  // bf16 1.0 x8
    f32x4 o[4][4] = {};
    f32x4 osum[4] = {};

    load_kv(0);
    write_kv(0);
    __syncthreads();
    load_kv(1);   // in flight during first compute

    const int NT = KQ / 64;
    for (int kt = 0; kt < NT; ++kt) {
        const int p = kt & 1;

        // ---- half-tile A: k-rows 0..31 (nt 0,1) --------------------------
        // S^T = K Q^T : lane holds S^T[k=nt*16+quad*4+i][q=w*64+qf*16+lx]
        f32x4 sv[2][4] = {};
#pragma unroll
        for (int ks = 0; ks < 2; ++ks)
#pragma unroll
            for (int nt = 0; nt < 2; ++nt) {
                f16x8 ak = *(const f16x8*)&Ks[p][nt * 16 + lx][ks * 32 + quad * 8];
#pragma unroll
                for (int qf = 0; qf < 4; ++qf)
                    sv[nt][qf] = __builtin_amdgcn_mfma_f32_16x16x32_f16(ak, qreg[qf][ks], sv[nt][qf], 0, 0, 0);
            }

        // stage next tile into the other buffer (regs loaded last iter;
        // safe: all reads of buf p^1 retired before last iter's barrier)
        if (kt < NT - 1) write_kv(p ^ 1);

        // p = exp2(s); pack to bf16; cross-quad redistribute via
        // permlane32_swap + permlane16_swap (VALU, no LDS round-trip)
        bf16x8 ap0[4];
#pragma unroll
        for (int qf = 0; qf < 4; ++qf) {
            u32 pu[2], pw[2];
#pragma unroll
            for (int nt = 0; nt < 2; ++nt) {
                u32 ub[4];
#pragma unroll
                for (int i = 0; i < 4; ++i)
                    ub[i] = __float_as_uint(__builtin_amdgcn_exp2f(sv[nt][qf][i]));
                pu[nt] = __builtin_amdgcn_perm(ub[1], ub[0], 0x07060302u);
                pw[nt] = __builtin_amdgcn_perm(ub[3], ub[2], 0x07060302u);
            }
            u32x2 r  = __builtin_amdgcn_permlane32_swap(pu[0], pu[1], false, false);
            u32x2 r2 = __builtin_amdgcn_permlane16_swap(r[0], r[1], false, false);
            u32x2 tt = __builtin_amdgcn_permlane32_swap(pw[0], pw[1], false, false);
            u32x2 t2 = __builtin_amdgcn_permlane16_swap(tt[0], tt[1], false, false);
            union { u32 d[4]; bf16x8 h; } cvt;
            cvt.d[0] = r2[0];
            cvt.d[1] = t2[0];
            cvt.d[2] = r2[1];
            cvt.d[3] = t2[1];
            ap0[qf] = cvt.h;
        }

        // PV ks=0 (k 0..31) + row sums
        __builtin_amdgcn_s_setprio(1);
#pragma unroll
        for (int qf = 0; qf < 4; ++qf)
            osum[qf] = __builtin_amdgcn_mfma_f32_16x16x32_bf16(ap0[qf], vone, osum[qf], 0, 0, 0);
#pragma unroll
        for (int nt = 0; nt < 4; ++nt) {
            bf16x8 bv = *(const bf16x8*)&Vs[p][nt * 16 + lx][quad * 8];
#pragma unroll
            for (int qf = 0; qf < 4; ++qf)
                o[qf][nt] = __builtin_amdgcn_mfma_f32_16x16x32_bf16(ap0[qf], bv, o[qf][nt], 0, 0, 0);
        }
        __builtin_amdgcn_s_setprio(0);

        // ---- half-tile B: k-rows 32..63 (nt 2,3) -------------------------
#pragma unroll
        for (int nt = 0; nt < 2; ++nt)
#pragma unroll
            for (int qf = 0; qf < 4; ++qf)
                sv[nt][qf] = (f32x4){0.f, 0.f, 0.f, 0.f};
#pragma unroll
        for (int ks = 0; ks < 2; ++ks)
#pragma unroll
            for (int nt = 0; nt < 2; ++nt) {
                f16x8 ak = *(const f16x8*)&Ks[p][(nt + 2) * 16 + lx][ks * 32 + quad * 8];
#pragma unroll
                for (int qf = 0; qf < 4; ++qf)
                    sv[nt][qf] = __builtin_amdgcn_mfma_f32_16x16x32_f16(ak, qreg[qf][ks], sv[nt][qf], 0, 0, 0);
            }

        bf16x8 ap1[4];
#pragma unroll
        for (int qf = 0; qf < 4; ++qf) {
            u32 pu[2], pw[2];
#pragma unroll
            for (int nt = 0; nt < 2; ++nt) {
                u32 ub[4];
#pragma unroll
                for (int i = 0; i < 4; ++i)
                    ub[i] = __float_as_uint(__builtin_amdgcn_exp2f(sv[nt][qf][i]));
                pu[nt] = __builtin_amdgcn_perm(ub[1], ub[0], 0x07060302u);
                pw[nt] = __builtin_amdgcn_perm(ub[3], ub[2], 0x07060302u);
            }
            u32x2 r  = __builtin_amdgcn_permlane32_swap(pu[0], pu[1], false, false);
            u32x2 r2 = __builtin_amdgcn_permlane16_swap(r[0], r[1], false, false);
            u32x2 tt = __builtin_amdgcn_permlane32_swap(pw[0], pw[1], false, false);
            u32x2 t2 = __builtin_amdgcn_permlane16_swap(tt[0], tt[1], false, false);
            union { u32 d[4]; bf16x8 h; } cvt;
            cvt.d[0] = r2[0];
            cvt.d[1] = t2[0];
            cvt.d[2] = r2[1];
            cvt.d[3] = t2[1];
            ap1[qf] = cvt.h;
        }

        // PV ks=1 (k 32..63) + row sums
        __builtin_amdgcn_s_setprio(1);
#pragma unroll
        for (int qf = 0; qf < 4; ++qf)
            osum[qf] = __builtin_amdgcn_mfma_f32_16x16x32_bf16(ap1[qf], vone, osum[qf], 0, 0, 0);
#pragma unroll
        for (int nt = 0; nt < 4; ++nt) {
            bf16x8 bv = *(const bf16x8*)&Vs[p][nt * 16 + lx][32 + quad * 8];
#pragma unroll
            for (int qf = 0; qf < 4; ++qf)
                o[qf][nt] = __builtin_amdgcn_mfma_f32_16x16x32_bf16(ap1[qf], bv, o[qf][nt], 0, 0, 0);
        }
        __builtin_amdgcn_s_setprio(0);

        if (kt < NT - 2) load_kv(kt + 2);  // next-next tile into regs
        if (kt < NT - 1) __syncthreads();  // ONE barrier per kt (dbuf)
    }

    // write On = O/l (fp16, [B,L,H*D]) and l (f32)
    const int b = bh >> 3, h = bh & 7;
    u16* Op = On + (size_t)s * M_ * F_;
#pragma unroll
    for (int qf = 0; qf < 4; ++qf) {
        float linv[4];
#pragma unroll
        for (int i = 0; i < 4; ++i) linv[i] = 1.f / osum[qf][i];
#pragma unroll
        for (int nt = 0; nt < 4; ++nt)
#pragma unroll
            for (int i = 0; i < 4; ++i) {
                int l = q0 + w * 64 + qf * 16 + quad * 4 + i;
                Op[((size_t)b * L_ + l) * (H_ * D_) + h * D_ + nt * 16 + lx] =
                    f2h(o[qf][nt][i] * linv[i]);
            }
        if (lx == 0) {
            float* lp = Ls + ((size_t)s * (B_ * H_) + bh) * L_ +
                        q0 + w * 64 + qf * 16 + quad * 4;
#pragma unroll
            for (int i = 0; i < 4; ++i) lp[i] = osum[qf][i];
        }
    }
}

// ---------------------------------------------------------------------------
// Combine split-K partials: O = sum_s l_s*O_s_n / sum_s l_s  (NSPL=4).
// ---------------------------------------------------------------------------
__global__ __launch_bounds__(256) void reduce_kernel(
    const u16* __restrict__ On, const float* __restrict__ Ls,
    u16* __restrict__ Ow) {
    const size_t MF = (size_t)M_ * F_;
    const int BHL = B_ * H_ * L_;
    int gid = blockIdx.x * 256 + threadIdx.x;  // u16x8 group, grid covers M_*F_/8
    size_t off = (size_t)gid * 8;
    int row = gid >> 3;                        // 64 elems per (b,l,h) row
    int b = row >> 15, rem = row & 32767;
    int l = rem >> 3, h = rem & 7;
    int lidx = ((b * H_ + h) << 12) + l;
    float lw[NSPL];
    float lt = 0.f;
#pragma unroll
    for (int s = 0; s < NSPL; ++s) { lw[s] = Ls[s * BHL + lidx]; lt += lw[s]; }
    float li = 1.f / lt;
    float r[8] = {};
#pragma unroll
    for (int s = 0; s < NSPL; ++s) {
        float ws = lw[s] * li;
        u16x8 a = *(const u16x8*)(On + s * MF + off);
#pragma unroll
        for (int j = 0; j < 8; ++j) r[j] += ws * h2f(a[j]);
    }
    u16 q[8];
#pragma unroll
    for (int j = 0; j < 8; ++j) q[j] = f2h(r[j]);
    *(u16x8*)(Ow + off) = *(u16x8*)q;
}

// ---------------------------------------------------------------------------
extern "C" void kernel_launch(void* const* d_in, const int* in_sizes, int n_in,
                              void* d_out, int out_size, void* d_ws, size_t ws_size,
                              hipStream_t stream)
{
    const float* Xq  = (const float*)d_in[0];
    const float* Xkv = (const float*)d_in[1];
    const float* Wq  = (const float*)d_in[2];
    const float* Wk  = (const float*)d_in[3];
    const float* Wv  = (const float*)d_in[4];
    const float* Wo  = (const float*)d_in[5];
    float* out = (float*)d_out;

    u16* ws  = (u16*)d_ws;
    const size_t MF = (size_t)M_ * F_;
    const size_t FF = (size_t)F_ * F_;
    u16* Wqt = ws;             // W^T 512x512 fp16 each
    u16* Wkt = Wqt + FF;
    u16* Wvt = Wkt + FF;
    u16* Wot = Wvt + FF;
    u16* Qw  = Wot + FF;       // [B,H,L,D] fp16, pre-scaled by log2e
    u16* Kw  = Qw + MF;        // [B,H,L,D] fp16
    u16* Vw  = Kw + MF;        // [B,H,D,L] bf16
    u16* On  = Vw + MF;        // NSPL x [B,L,H*D] fp16 split partials
    float* Ls = (float*)(On + NSPL * MF);  // NSPL x [BH, L] f32
    u16* Ow  = Qw;             // reduced O aliases Qw (dead after flash)

    wt_kernel<<<dim3(16, 16, 4), 256, 0, stream>>>(Wq, Wk, Wv, Wo,
                                                   Wqt, Wkt, Wvt, Wot);

    proj_kernel<<<dim3(8, 64, 2), 256, 0, stream>>>(Xq, Xkv, Wqt, Wkt, Wvt,
                                                    Qw, Kw, Vw);

    flash_mfma<<<dim3(1024), 256, 0, stream>>>(Qw, Kw, Vw, On, Ls);

    reduce_kernel<<<dim3((int)(MF / 8 / 256)), 256, 0, stream>>>(On, Ls, Ow);

    out_gemm<<<dim3(8, 64), 256, 0, stream>>>(Ow, Wot, out);
}

// Round 6
// 219.374 us; speedup vs baseline: 2.8020x; 2.8020x over previous
//
#include <hip/hip_runtime.h>
#include <hip/hip_bf16.h>

typedef short bf16x8 __attribute__((ext_vector_type(8)));
typedef _Float16 f16;
typedef f16 f16x8 __attribute__((ext_vector_type(8)));
typedef float f32x4 __attribute__((ext_vector_type(4)));
typedef unsigned short u16;
typedef u16 u16x8 __attribute__((ext_vector_type(8)));
typedef unsigned int u32;
typedef u32 u32x2 __attribute__((ext_vector_type(2)));

#define B_  2
#define L_  4096
#define F_  512
#define H_  8
#define D_  64
#define M_  8192       // B_*L_
#define NSPL 4         // flash split-K factor (grid 1024 -> 4 blocks/CU)
#define KQ  (L_ / NSPL)

#define LOG2E 1.442695041f

__device__ inline u16 f2bf(float f) {
    union { float f; unsigned u; } v; v.f = f;
    unsigned r = v.u + 0x7fff + ((v.u >> 16) & 1);  // RNE
    return (u16)(r >> 16);
}
__device__ inline u16 f2h(float f) {
    union { f16 h; u16 u; } v; v.h = (f16)f;  // RNE hw cvt
    return v.u;
}
__device__ inline float h2f(u16 u) {
    union { u16 u; f16 h; } v; v.u = u;
    return (float)v.h;
}

// ---------------------------------------------------------------------------
// Fused weight transpose: W [512 k][512 n] fp32 -> Wt [512 n][512 k] fp16.
// ---------------------------------------------------------------------------
__global__ __launch_bounds__(256) void wt_kernel(
    const float* __restrict__ Wq, const float* __restrict__ Wk,
    const float* __restrict__ Wv, const float* __restrict__ Wo,
    u16* __restrict__ Tq, u16* __restrict__ Tk,
    u16* __restrict__ Tv, u16* __restrict__ To) {
    __shared__ float t[32][33];
    const int z = blockIdx.z;
    const float* in = (z == 0) ? Wq : (z == 1) ? Wk : (z == 2) ? Wv : Wo;
    u16* out = (z == 0) ? Tq : (z == 1) ? Tk : (z == 2) ? Tv : To;
    int k0 = blockIdx.y * 32, n0 = blockIdx.x * 32;
    int c = threadIdx.x & 31, r8 = threadIdx.x >> 5;
#pragma unroll
    for (int i = 0; i < 4; ++i) {
        int r = r8 * 4 + i;
        t[r][c] = in[(size_t)(k0 + r) * F_ + n0 + c];
    }
    __syncthreads();
#pragma unroll
    for (int i = 0; i < 4; ++i) {
        int r = r8 * 4 + i;
        out[(size_t)(n0 + r) * F_ + k0 + c] = f2h(t[c][r]);
    }
}

// ---------------------------------------------------------------------------
// Fused projection kernel, 128x64 tile, register prefetch (loads issued
// AFTER the barrier pair so no barrier drains a fresh vmcnt).
// z=0: Q = Xq*Wq (scaled log2e) -> [B,H,L,D] fp16.
// z=1: K -> [B,H,L,D] fp16;  V -> [B,H,D,L] bf16 transposed.
// ---------------------------------------------------------------------------
__global__ __launch_bounds__(256, 3) void proj_kernel(
    const float* __restrict__ Xq, const float* __restrict__ Xkv,
    const u16* __restrict__ Wqt, const u16* __restrict__ Wkt,
    const u16* __restrict__ Wvt,
    u16* __restrict__ Qw, u16* __restrict__ Kw, u16* __restrict__ Vw) {
    __shared__ u16 Ah[128][72];
    __shared__ u16 B1[64][72];
    __shared__ u16 B2[64][72];
    const int tid = threadIdx.x;
    const int w = tid >> 6, lane = tid & 63, lx = lane & 15, quad = lane >> 4;
    const int m0 = blockIdx.y * 128, n0 = blockIdx.x * 64;
    const bool isKV = (blockIdx.z == 1);
    const float* A = isKV ? Xkv : Xq;
    const u16* W1 = isKV ? Wkt : Wqt;

    float4 apre[8];
    u16x8 b1p[2], b2p[2];

    auto load_ab = [&](int k0) {
#pragma unroll
        for (int it = 0; it < 4; ++it) {
            int slot = tid + it * 256, r = slot >> 3, g = (slot & 7) * 8;
            apre[2 * it]     = *(const float4*)(A + (size_t)(m0 + r) * F_ + k0 + g);
            apre[2 * it + 1] = *(const float4*)(A + (size_t)(m0 + r) * F_ + k0 + g + 4);
        }
#pragma unroll
        for (int it = 0; it < 2; ++it) {
            int slot = tid + it * 256, r = slot >> 3, g = (slot & 7) * 8;
            b1p[it] = *(const u16x8*)(W1 + (size_t)(n0 + r) * F_ + k0 + g);
            if (isKV)
                b2p[it] = *(const u16x8*)(Wvt + (size_t)(n0 + r) * F_ + k0 + g);
        }
    };
    auto write_ab = [&]() {
#pragma unroll
        for (int it = 0; it < 4; ++it) {
            int slot = tid + it * 256, r = slot >> 3, g = (slot & 7) * 8;
            float4 f0 = apre[2 * it], f1 = apre[2 * it + 1];
            u16 th[8] = {f2h(f0.x), f2h(f0.y), f2h(f0.z), f2h(f0.w),
                         f2h(f1.x), f2h(f1.y), f2h(f1.z), f2h(f1.w)};
            *(u16x8*)&Ah[r][g] = *(u16x8*)th;
        }
#pragma unroll
        for (int it = 0; it < 2; ++it) {
            int slot = tid + it * 256, r = slot >> 3, g = (slot & 7) * 8;
            *(u16x8*)&B1[r][g] = b1p[it];
            if (isKV) *(u16x8*)&B2[r][g] = b2p[it];
        }
    };

    f32x4 acc1[2][4] = {}, acc2[2][4] = {};

    load_ab(0);
    write_ab();
    __syncthreads();
    load_ab(64);   // in flight during first compute

    for (int k0 = 0; k0 < F_; k0 += 64) {
#pragma unroll
        for (int ks = 0; ks < 2; ++ks) {
            f16x8 af[2];
#pragma unroll
            for (int mf = 0; mf < 2; ++mf)
                af[mf] = *(const f16x8*)&Ah[w * 32 + mf * 16 + lx][ks * 32 + quad * 8];
#pragma unroll
            for (int nt = 0; nt < 4; ++nt) {
                f16x8 b1 = *(const f16x8*)&B1[nt * 16 + lx][ks * 32 + quad * 8];
#pragma unroll
                for (int mf = 0; mf < 2; ++mf)
                    acc1[mf][nt] = __builtin_amdgcn_mfma_f32_16x16x32_f16(af[mf], b1, acc1[mf][nt], 0, 0, 0);
                if (isKV) {
                    f16x8 b2 = *(const f16x8*)&B2[nt * 16 + lx][ks * 32 + quad * 8];
#pragma unroll
                    for (int mf = 0; mf < 2; ++mf)
                        acc2[mf][nt] = __builtin_amdgcn_mfma_f32_16x16x32_f16(af[mf], b2, acc2[mf][nt], 0, 0, 0);
                }
            }
        }
        if (k0 < F_ - 64) {
            __syncthreads();   // loads for k0+64 landed during this compute
            write_ab();
            __syncthreads();
            if (k0 < F_ - 128) load_ab(k0 + 128);  // issued AFTER barriers
        }
    }

    const int h = n0 >> 6;
    const float scl = isKV ? 1.0f : LOG2E;
    u16* C1 = isKV ? Kw : Qw;
#pragma unroll
    for (int mf = 0; mf < 2; ++mf)
#pragma unroll
        for (int nt = 0; nt < 4; ++nt)
#pragma unroll
            for (int i = 0; i < 4; ++i) {
                int m = m0 + w * 32 + mf * 16 + quad * 4 + i;
                int b = m >> 12, l = m & 4095;
                int d = nt * 16 + lx;
                C1[((size_t)(b * H_ + h) * L_ + l) * D_ + d] = f2h(acc1[mf][nt][i] * scl);
            }
    if (isKV) {
        __syncthreads();
#pragma unroll
        for (int mf = 0; mf < 2; ++mf)
#pragma unroll
            for (int nt = 0; nt < 4; ++nt)
#pragma unroll
                for (int i = 0; i < 4; ++i)
                    Ah[w * 32 + mf * 16 + quad * 4 + i][nt * 16 + lx] = f2bf(acc2[mf][nt][i]);
        __syncthreads();
        int d = tid >> 2, seg = (tid & 3) * 32;
        int b = m0 >> 12;
        u16 tmp[32];
#pragma unroll
        for (int j = 0; j < 32; ++j) tmp[j] = Ah[seg + j][d];
        size_t base = ((size_t)(b * H_ + h) * D_ + d) * L_ + (m0 & 4095) + seg;
#pragma unroll
        for (int c = 0; c < 4; ++c)
            *(u16x8*)(Vw + base + c * 8) = *(u16x8*)&tmp[c * 8];
    }
}

// ---------------------------------------------------------------------------
// Out-projection GEMM, 128x64 tile: A fp16 x Wt fp16 -> C fp32.
// (R4 lesson: fusing the split-K combine here recomputes it per n0-tile
// (8x) and doubles A traffic — net −11 µs. Keep reduce separate.)
// ---------------------------------------------------------------------------
__global__ __launch_bounds__(256) void out_gemm(const u16* __restrict__ A16,
                                                const u16* __restrict__ Wt,
                                                float* __restrict__ Cf) {
    __shared__ u16 As[128][72];
    __shared__ u16 Bs[64][72];
    const int tid = threadIdx.x;
    const int w = tid >> 6, lane = tid & 63, lx = lane & 15, quad = lane >> 4;
    const int m0 = blockIdx.y * 128, n0 = blockIdx.x * 64;

    u16x8 a16p[4];
    u16x8 bp[2];

    auto load_ab = [&](int k0) {
#pragma unroll
        for (int it = 0; it < 4; ++it) {
            int slot = tid + it * 256, r = slot >> 3, g = (slot & 7) * 8;
            a16p[it] = *(const u16x8*)(A16 + (size_t)(m0 + r) * F_ + k0 + g);
        }
#pragma unroll
        for (int it = 0; it < 2; ++it) {
            int slot = tid + it * 256, r = slot >> 3, g = (slot & 7) * 8;
            bp[it] = *(const u16x8*)(Wt + (size_t)(n0 + r) * F_ + k0 + g);
        }
    };
    auto write_ab = [&]() {
#pragma unroll
        for (int it = 0; it < 4; ++it) {
            int slot = tid + it * 256, r = slot >> 3, g = (slot & 7) * 8;
            *(u16x8*)&As[r][g] = a16p[it];
        }
#pragma unroll
        for (int it = 0; it < 2; ++it) {
            int slot = tid + it * 256, r = slot >> 3, g = (slot & 7) * 8;
            *(u16x8*)&Bs[r][g] = bp[it];
        }
    };

    f32x4 acc[2][4] = {};

    load_ab(0);
    write_ab();
    __syncthreads();
    load_ab(64);

    for (int k0 = 0; k0 < F_; k0 += 64) {
#pragma unroll
        for (int ks = 0; ks < 2; ++ks) {
            f16x8 af[2];
#pragma unroll
            for (int mf = 0; mf < 2; ++mf)
                af[mf] = *(const f16x8*)&As[w * 32 + mf * 16 + lx][ks * 32 + quad * 8];
#pragma unroll
            for (int nt = 0; nt < 4; ++nt) {
                f16x8 bf = *(const f16x8*)&Bs[nt * 16 + lx][ks * 32 + quad * 8];
#pragma unroll
                for (int mf = 0; mf < 2; ++mf)
                    acc[mf][nt] = __builtin_amdgcn_mfma_f32_16x16x32_f16(af[mf], bf, acc[mf][nt], 0, 0, 0);
            }
        }
        if (k0 < F_ - 64) {
            __syncthreads();
            write_ab();
            __syncthreads();
            if (k0 < F_ - 128) load_ab(k0 + 128);
        }
    }

#pragma unroll
    for (int mf = 0; mf < 2; ++mf)
#pragma unroll
        for (int nt = 0; nt < 4; ++nt)
#pragma unroll
            for (int i = 0; i < 4; ++i) {
                int m = m0 + w * 32 + mf * 16 + quad * 4 + i;
                int n = n0 + nt * 16 + lx;
                Cf[(size_t)m * F_ + n] = acc[mf][nt][i];
            }
}

// ---------------------------------------------------------------------------
// MFMA flash attention, R6: R2 structure (VERIFIED 83.7 us) with NSPL=4,
// keeping __launch_bounds__(256,2) — the R5 lesson: (256,4) forced the
// allocator to 64 VGPR and the ~130-reg live set spilled (940 MB scratch
// fetch). At the natural 96 VGPR the HARDWARE already permits 4 blocks/CU
// (96 <= 128-VGPR occupancy step, LDS 4x36.9=147.5 <= 160 KB), so grid
// 1024 alone doubles waves/SIMD to 4 — out-of-phase waves fill the
// matrix-pipe gaps during softmax (R2: MfmaUtil 39, VALUBusy 45, neither
// saturated = latency-bound at TLP 2).
// BQ=256 (4 waves x 64q, qf=4), Q in regs, P in regs (permlane swap),
// K/V in LDS double-buffer, ONE barrier per kt.
// XCD swizzle: (x&7) -> 2 heads per XCD.
// ---------------------------------------------------------------------------
__global__ __launch_bounds__(256, 2) void flash_mfma(
    const u16* __restrict__ Qg, const u16* __restrict__ Kg,
    const u16* __restrict__ Vtg, u16* __restrict__ On, float* __restrict__ Ls) {
    __shared__ u16 Ks[2][64][72];   // fp16, double-buffered
    __shared__ u16 Vs[2][64][72];   // bf16, V^T tile [d][kcol], double-buffered

    const int tid = threadIdx.x;
    const int w = tid >> 6, lane = tid & 63, lx = lane & 15, quad = lane >> 4;

    // decode: 1024 = 8 xcd * (2 head * 4 split * 16 qtile)
    const int x = blockIdx.x;
    const int t = x >> 3;              // 0..127 within xcd
    const int hh = t >> 6;             // 0..1
    const int s = (t >> 4) & 3;        // 0..3 split
    const int bh = (x & 7) * 2 + hh;
    const int q0 = (t & 15) * 256;

    const u16* Qp = Qg + ((size_t)bh * L_ + q0) * D_;
    const u16* Kp = Kg + (size_t)bh * L_ * D_ + (size_t)(s * KQ) * D_;
    const u16* Vp = Vtg + (size_t)bh * D_ * L_ + s * KQ;

    // Q fragments straight to registers (B-operand layout), 64 q-rows/wave
    f16x8 qreg[4][2];
#pragma unroll
    for (int qf = 0; qf < 4; ++qf)
#pragma unroll
        for (int ks = 0; ks < 2; ++ks)
            qreg[qf][ks] = *(const f16x8*)(Qp + (size_t)(w * 64 + qf * 16 + lx) * D_ +
                                           ks * 32 + quad * 8);

    u16x8 kp[2], vp[2];
    auto load_kv = [&](int kt) {
#pragma unroll
        for (int it = 0; it < 2; ++it) {
            int slot = tid + it * 256, r = slot >> 3, g = (slot & 7) * 8;
            kp[it] = *(const u16x8*)(Kp + (size_t)(kt * 64 + r) * D_ + g);
            vp[it] = *(const u16x8*)(Vp + (size_t)r * L_ + kt * 64 + g);
        }
    };
    auto write_kv = [&](int p) {
#pragma unroll
        for (int it = 0; it < 2; ++it) {
            int slot = tid + it * 256, r = slot >> 3, g = (slot & 7) * 8;
            *(u16x8*)&Ks[p][r][g] = kp[it];
            *(u16x8*)&Vs[p][r][g] = vp[it];
        }
    };

    const bf16x8 vone = {0x3F80, 0x3F80, 0x3F80, 0x3F80,
                         0x3F80, 0x3F80, 0x3F80, 0x3F80};  // bf16 1.0 x8
    f32x4 o[4][4] = {};
    f32x4 osum[4] = {};

    load_kv(0);
    write_kv(0);
    __syncthreads();
    load_kv(1);   // in flight during first compute

    const int NT = KQ / 64;
    for (int kt = 0; kt < NT; ++kt) {
        const int p = kt & 1;

        // ---- half-tile A: k-rows 0..31 (nt 0,1) --------------------------
        // S^T = K Q^T : lane holds S^T[k=nt*16+quad*4+i][q=w*64+qf*16+lx]
        f32x4 sv[2][4] = {};
#pragma unroll
        for (int ks = 0; ks < 2; ++ks)
#pragma unroll
            for (int nt = 0; nt < 2; ++nt) {
                f16x8 ak = *(const f16x8*)&Ks[p][nt * 16 + lx][ks * 32 + quad * 8];
#pragma unroll
                for (int qf = 0; qf < 4; ++qf)
                    sv[nt][qf] = __builtin_amdgcn_mfma_f32_16x16x32_f16(ak, qreg[qf][ks], sv[nt][qf], 0, 0, 0);
            }

        // stage next tile into the other buffer (regs loaded last iter;
        // safe: all reads of buf p^1 retired before last iter's barrier)
        if (kt < NT - 1) write_kv(p ^ 1);

        // p = exp2(s); pack to bf16; cross-quad redistribute via
        // permlane32_swap + permlane16_swap (VALU, no LDS round-trip)
        bf16x8 ap0[4];
#pragma unroll
        for (int qf = 0; qf < 4; ++qf) {
            u32 pu[2], pw[2];
#pragma unroll
            for (int nt = 0; nt < 2; ++nt) {
                u32 ub[4];
#pragma unroll
                for (int i = 0; i < 4; ++i)
                    ub[i] = __float_as_uint(__builtin_amdgcn_exp2f(sv[nt][qf][i]));
                pu[nt] = __builtin_amdgcn_perm(ub[1], ub[0], 0x07060302u);
                pw[nt] = __builtin_amdgcn_perm(ub[3], ub[2], 0x07060302u);
            }
            u32x2 r  = __builtin_amdgcn_permlane32_swap(pu[0], pu[1], false, false);
            u32x2 r2 = __builtin_amdgcn_permlane16_swap(r[0], r[1], false, false);
            u32x2 tt = __builtin_amdgcn_permlane32_swap(pw[0], pw[1], false, false);
            u32x2 t2 = __builtin_amdgcn_permlane16_swap(tt[0], tt[1], false, false);
            union { u32 d[4]; bf16x8 h; } cvt;
            cvt.d[0] = r2[0];
            cvt.d[1] = t2[0];
            cvt.d[2] = r2[1];
            cvt.d[3] = t2[1];
            ap0[qf] = cvt.h;
        }

        // PV ks=0 (k 0..31) + row sums
        __builtin_amdgcn_s_setprio(1);
#pragma unroll
        for (int qf = 0; qf < 4; ++qf)
            osum[qf] = __builtin_amdgcn_mfma_f32_16x16x32_bf16(ap0[qf], vone, osum[qf], 0, 0, 0);
#pragma unroll
        for (int nt = 0; nt < 4; ++nt) {
            bf16x8 bv = *(const bf16x8*)&Vs[p][nt * 16 + lx][quad * 8];
#pragma unroll
            for (int qf = 0; qf < 4; ++qf)
                o[qf][nt] = __builtin_amdgcn_mfma_f32_16x16x32_bf16(ap0[qf], bv, o[qf][nt], 0, 0, 0);
        }
        __builtin_amdgcn_s_setprio(0);

        // ---- half-tile B: k-rows 32..63 (nt 2,3) -------------------------
#pragma unroll
        for (int nt = 0; nt < 2; ++nt)
#pragma unroll
            for (int qf = 0; qf < 4; ++qf)
                sv[nt][qf] = (f32x4){0.f, 0.f, 0.f, 0.f};
#pragma unroll
        for (int ks = 0; ks < 2; ++ks)
#pragma unroll
            for (int nt = 0; nt < 2; ++nt) {
                f16x8 ak = *(const f16x8*)&Ks[p][(nt + 2) * 16 + lx][ks * 32 + quad * 8];
#pragma unroll
                for (int qf = 0; qf < 4; ++qf)
                    sv[nt][qf] = __builtin_amdgcn_mfma_f32_16x16x32_f16(ak, qreg[qf][ks], sv[nt][qf], 0, 0, 0);
            }

        bf16x8 ap1[4];
#pragma unroll
        for (int qf = 0; qf < 4; ++qf) {
            u32 pu[2], pw[2];
#pragma unroll
            for (int nt = 0; nt < 2; ++nt) {
                u32 ub[4];
#pragma unroll
                for (int i = 0; i < 4; ++i)
                    ub[i] = __float_as_uint(__builtin_amdgcn_exp2f(sv[nt][qf][i]));
                pu[nt] = __builtin_amdgcn_perm(ub[1], ub[0], 0x07060302u);
                pw[nt] = __builtin_amdgcn_perm(ub[3], ub[2], 0x07060302u);
            }
            u32x2 r  = __builtin_amdgcn_permlane32_swap(pu[0], pu[1], false, false);
            u32x2 r2 = __builtin_amdgcn_permlane16_swap(r[0], r[1], false, false);
            u32x2 tt = __builtin_amdgcn_permlane32_swap(pw[0], pw[1], false, false);
            u32x2 t2 = __builtin_amdgcn_permlane16_swap(tt[0], tt[1], false, false);
            union { u32 d[4]; bf16x8 h; } cvt;
            cvt.d[0] = r2[0];
            cvt.d[1] = t2[0];
            cvt.d[2] = r2[1];
            cvt.d[3] = t2[1];
            ap1[qf] = cvt.h;
        }

        // PV ks=1 (k 32..63) + row sums
        __builtin_amdgcn_s_setprio(1);
#pragma unroll
        for (int qf = 0; qf < 4; ++qf)
            osum[qf] = __builtin_amdgcn_mfma_f32_16x16x32_bf16(ap1[qf], vone, osum[qf], 0, 0, 0);
#pragma unroll
        for (int nt = 0; nt < 4; ++nt) {
            bf16x8 bv = *(const bf16x8*)&Vs[p][nt * 16 + lx][32 + quad * 8];
#pragma unroll
            for (int qf = 0; qf < 4; ++qf)
                o[qf][nt] = __builtin_amdgcn_mfma_f32_16x16x32_bf16(ap1[qf], bv, o[qf][nt], 0, 0, 0);
        }
        __builtin_amdgcn_s_setprio(0);

        if (kt < NT - 2) load_kv(kt + 2);  // next-next tile into regs
        if (kt < NT - 1) __syncthreads();  // ONE barrier per kt (dbuf)
    }

    // write On = O/l (fp16, [B,L,H*D]) and l (f32)
    const int b = bh >> 3, h = bh & 7;
    u16* Op = On + (size_t)s * M_ * F_;
#pragma unroll
    for (int qf = 0; qf < 4; ++qf) {
        float linv[4];
#pragma unroll
        for (int i = 0; i < 4; ++i) linv[i] = 1.f / osum[qf][i];
#pragma unroll
        for (int nt = 0; nt < 4; ++nt)
#pragma unroll
            for (int i = 0; i < 4; ++i) {
                int l = q0 + w * 64 + qf * 16 + quad * 4 + i;
                Op[((size_t)b * L_ + l) * (H_ * D_) + h * D_ + nt * 16 + lx] =
                    f2h(o[qf][nt][i] * linv[i]);
            }
        if (lx == 0) {
            float* lp = Ls + ((size_t)s * (B_ * H_) + bh) * L_ +
                        q0 + w * 64 + qf * 16 + quad * 4;
#pragma unroll
            for (int i = 0; i < 4; ++i) lp[i] = osum[qf][i];
        }
    }
}

// ---------------------------------------------------------------------------
// Combine split-K partials: O = sum_s l_s*O_s_n / sum_s l_s  (NSPL=4).
// ---------------------------------------------------------------------------
__global__ __launch_bounds__(256) void reduce_kernel(
    const u16* __restrict__ On, const float* __restrict__ Ls,
    u16* __restrict__ Ow) {
    const size_t MF = (size_t)M_ * F_;
    const int BHL = B_ * H_ * L_;
    int gid = blockIdx.x * 256 + threadIdx.x;  // u16x8 group, grid covers M_*F_/8
    size_t off = (size_t)gid * 8;
    int row = gid >> 3;                        // 64 elems per (b,l,h) row
    int b = row >> 15, rem = row & 32767;
    int l = rem >> 3, h = rem & 7;
    int lidx = ((b * H_ + h) << 12) + l;
    float lw[NSPL];
    float lt = 0.f;
#pragma unroll
    for (int s = 0; s < NSPL; ++s) { lw[s] = Ls[s * BHL + lidx]; lt += lw[s]; }
    float li = 1.f / lt;
    float r[8] = {};
#pragma unroll
    for (int s = 0; s < NSPL; ++s) {
        float ws = lw[s] * li;
        u16x8 a = *(const u16x8*)(On + s * MF + off);
#pragma unroll
        for (int j = 0; j < 8; ++j) r[j] += ws * h2f(a[j]);
    }
    u16 q[8];
#pragma unroll
    for (int j = 0; j < 8; ++j) q[j] = f2h(r[j]);
    *(u16x8*)(Ow + off) = *(u16x8*)q;
}

// ---------------------------------------------------------------------------
extern "C" void kernel_launch(void* const* d_in, const int* in_sizes, int n_in,
                              void* d_out, int out_size, void* d_ws, size_t ws_size,
                              hipStream_t stream)
{
    const float* Xq  = (const float*)d_in[0];
    const float* Xkv = (const float*)d_in[1];
    const float* Wq  = (const float*)d_in[2];
    const float* Wk  = (const float*)d_in[3];
    const float* Wv  = (const float*)d_in[4];
    const float* Wo  = (const float*)d_in[5];
    float* out = (float*)d_out;

    u16* ws  = (u16*)d_ws;
    const size_t MF = (size_t)M_ * F_;
    const size_t FF = (size_t)F_ * F_;
    u16* Wqt = ws;             // W^T 512x512 fp16 each
    u16* Wkt = Wqt + FF;
    u16* Wvt = Wkt + FF;
    u16* Wot = Wvt + FF;
    u16* Qw  = Wot + FF;       // [B,H,L,D] fp16, pre-scaled by log2e
    u16* Kw  = Qw + MF;        // [B,H,L,D] fp16
    u16* Vw  = Kw + MF;        // [B,H,D,L] bf16
    u16* On  = Vw + MF;        // NSPL x [B,L,H*D] fp16 split partials
    float* Ls = (float*)(On + NSPL * MF);  // NSPL x [BH, L] f32
    u16* Ow  = Qw;             // reduced O aliases Qw (dead after flash)

    wt_kernel<<<dim3(16, 16, 4), 256, 0, stream>>>(Wq, Wk, Wv, Wo,
                                                   Wqt, Wkt, Wvt, Wot);

    proj_kernel<<<dim3(8, 64, 2), 256, 0, stream>>>(Xq, Xkv, Wqt, Wkt, Wvt,
                                                    Qw, Kw, Vw);

    flash_mfma<<<dim3(1024), 256, 0, stream>>>(Qw, Kw, Vw, On, Ls);

    reduce_kernel<<<dim3((int)(MF / 8 / 256)), 256, 0, stream>>>(On, Ls, Ow);

    out_gemm<<<dim3(8, 64), 256, 0, stream>>>(Ow, Wot, out);
}

// Round 7
// 216.096 us; speedup vs baseline: 2.8445x; 1.0152x over previous
//
#include <hip/hip_runtime.h>
#include <hip/hip_bf16.h>

typedef short bf16x8 __attribute__((ext_vector_type(8)));
typedef _Float16 f16;
typedef f16 f16x8 __attribute__((ext_vector_type(8)));
typedef float f32x4 __attribute__((ext_vector_type(4)));
typedef unsigned short u16;
typedef u16 u16x8 __attribute__((ext_vector_type(8)));
typedef unsigned int u32;
typedef u32 u32x2 __attribute__((ext_vector_type(2)));

#define B_  2
#define L_  4096
#define F_  512
#define H_  8
#define D_  64
#define M_  8192       // B_*L_
#define NSPL 2         // flash split-K factor
#define KHALF (L_ / NSPL)

#define LOG2E 1.442695041f

__device__ inline u16 f2bf(float f) {
    union { float f; unsigned u; } v; v.f = f;
    unsigned r = v.u + 0x7fff + ((v.u >> 16) & 1);  // RNE
    return (u16)(r >> 16);
}
__device__ inline u16 f2h(float f) {
    union { f16 h; u16 u; } v; v.h = (f16)f;  // RNE hw cvt
    return v.u;
}
__device__ inline float h2f(u16 u) {
    union { u16 u; f16 h; } v; v.u = u;
    return (float)v.h;
}

// ---------------------------------------------------------------------------
// Fused weight transpose: W [512 k][512 n] fp32 -> Wt [512 n][512 k] fp16.
// ---------------------------------------------------------------------------
__global__ __launch_bounds__(256) void wt_kernel(
    const float* __restrict__ Wq, const float* __restrict__ Wk,
    const float* __restrict__ Wv, const float* __restrict__ Wo,
    u16* __restrict__ Tq, u16* __restrict__ Tk,
    u16* __restrict__ Tv, u16* __restrict__ To) {
    __shared__ float t[32][33];
    const int z = blockIdx.z;
    const float* in = (z == 0) ? Wq : (z == 1) ? Wk : (z == 2) ? Wv : Wo;
    u16* out = (z == 0) ? Tq : (z == 1) ? Tk : (z == 2) ? Tv : To;
    int k0 = blockIdx.y * 32, n0 = blockIdx.x * 32;
    int c = threadIdx.x & 31, r8 = threadIdx.x >> 5;
#pragma unroll
    for (int i = 0; i < 4; ++i) {
        int r = r8 * 4 + i;
        t[r][c] = in[(size_t)(k0 + r) * F_ + n0 + c];
    }
    __syncthreads();
#pragma unroll
    for (int i = 0; i < 4; ++i) {
        int r = r8 * 4 + i;
        out[(size_t)(n0 + r) * F_ + k0 + c] = f2h(t[c][r]);
    }
}

// ---------------------------------------------------------------------------
// Fused projection kernel, 128x64 tile, register prefetch (loads issued
// AFTER the barrier pair so no barrier drains a fresh vmcnt).
// z=0: Q = Xq*Wq (scaled log2e) -> [B,H,L,D] fp16.
// z=1: K -> [B,H,L,D] fp16;  V -> [B,H,D,L] bf16 transposed.
// ---------------------------------------------------------------------------
__global__ __launch_bounds__(256, 3) void proj_kernel(
    const float* __restrict__ Xq, const float* __restrict__ Xkv,
    const u16* __restrict__ Wqt, const u16* __restrict__ Wkt,
    const u16* __restrict__ Wvt,
    u16* __restrict__ Qw, u16* __restrict__ Kw, u16* __restrict__ Vw) {
    __shared__ u16 Ah[128][72];
    __shared__ u16 B1[64][72];
    __shared__ u16 B2[64][72];
    const int tid = threadIdx.x;
    const int w = tid >> 6, lane = tid & 63, lx = lane & 15, quad = lane >> 4;
    const int m0 = blockIdx.y * 128, n0 = blockIdx.x * 64;
    const bool isKV = (blockIdx.z == 1);
    const float* A = isKV ? Xkv : Xq;
    const u16* W1 = isKV ? Wkt : Wqt;

    float4 apre[8];
    u16x8 b1p[2], b2p[2];

    auto load_ab = [&](int k0) {
#pragma unroll
        for (int it = 0; it < 4; ++it) {
            int slot = tid + it * 256, r = slot >> 3, g = (slot & 7) * 8;
            apre[2 * it]     = *(const float4*)(A + (size_t)(m0 + r) * F_ + k0 + g);
            apre[2 * it + 1] = *(const float4*)(A + (size_t)(m0 + r) * F_ + k0 + g + 4);
        }
#pragma unroll
        for (int it = 0; it < 2; ++it) {
            int slot = tid + it * 256, r = slot >> 3, g = (slot & 7) * 8;
            b1p[it] = *(const u16x8*)(W1 + (size_t)(n0 + r) * F_ + k0 + g);
            if (isKV)
                b2p[it] = *(const u16x8*)(Wvt + (size_t)(n0 + r) * F_ + k0 + g);
        }
    };
    auto write_ab = [&]() {
#pragma unroll
        for (int it = 0; it < 4; ++it) {
            int slot = tid + it * 256, r = slot >> 3, g = (slot & 7) * 8;
            float4 f0 = apre[2 * it], f1 = apre[2 * it + 1];
            u16 th[8] = {f2h(f0.x), f2h(f0.y), f2h(f0.z), f2h(f0.w),
                         f2h(f1.x), f2h(f1.y), f2h(f1.z), f2h(f1.w)};
            *(u16x8*)&Ah[r][g] = *(u16x8*)th;
        }
#pragma unroll
        for (int it = 0; it < 2; ++it) {
            int slot = tid + it * 256, r = slot >> 3, g = (slot & 7) * 8;
            *(u16x8*)&B1[r][g] = b1p[it];
            if (isKV) *(u16x8*)&B2[r][g] = b2p[it];
        }
    };

    f32x4 acc1[2][4] = {}, acc2[2][4] = {};

    load_ab(0);
    write_ab();
    __syncthreads();
    load_ab(64);   // in flight during first compute

    for (int k0 = 0; k0 < F_; k0 += 64) {
#pragma unroll
        for (int ks = 0; ks < 2; ++ks) {
            f16x8 af[2];
#pragma unroll
            for (int mf = 0; mf < 2; ++mf)
                af[mf] = *(const f16x8*)&Ah[w * 32 + mf * 16 + lx][ks * 32 + quad * 8];
#pragma unroll
            for (int nt = 0; nt < 4; ++nt) {
                f16x8 b1 = *(const f16x8*)&B1[nt * 16 + lx][ks * 32 + quad * 8];
#pragma unroll
                for (int mf = 0; mf < 2; ++mf)
                    acc1[mf][nt] = __builtin_amdgcn_mfma_f32_16x16x32_f16(af[mf], b1, acc1[mf][nt], 0, 0, 0);
                if (isKV) {
                    f16x8 b2 = *(const f16x8*)&B2[nt * 16 + lx][ks * 32 + quad * 8];
#pragma unroll
                    for (int mf = 0; mf < 2; ++mf)
                        acc2[mf][nt] = __builtin_amdgcn_mfma_f32_16x16x32_f16(af[mf], b2, acc2[mf][nt], 0, 0, 0);
                }
            }
        }
        if (k0 < F_ - 64) {
            __syncthreads();   // loads for k0+64 landed during this compute
            write_ab();
            __syncthreads();
            if (k0 < F_ - 128) load_ab(k0 + 128);  // issued AFTER barriers
        }
    }

    const int h = n0 >> 6;
    const float scl = isKV ? 1.0f : LOG2E;
    u16* C1 = isKV ? Kw : Qw;
#pragma unroll
    for (int mf = 0; mf < 2; ++mf)
#pragma unroll
        for (int nt = 0; nt < 4; ++nt)
#pragma unroll
            for (int i = 0; i < 4; ++i) {
                int m = m0 + w * 32 + mf * 16 + quad * 4 + i;
                int b = m >> 12, l = m & 4095;
                int d = nt * 16 + lx;
                C1[((size_t)(b * H_ + h) * L_ + l) * D_ + d] = f2h(acc1[mf][nt][i] * scl);
            }
    if (isKV) {
        __syncthreads();
#pragma unroll
        for (int mf = 0; mf < 2; ++mf)
#pragma unroll
            for (int nt = 0; nt < 4; ++nt)
#pragma unroll
                for (int i = 0; i < 4; ++i)
                    Ah[w * 32 + mf * 16 + quad * 4 + i][nt * 16 + lx] = f2bf(acc2[mf][nt][i]);
        __syncthreads();
        int d = tid >> 2, seg = (tid & 3) * 32;
        int b = m0 >> 12;
        u16 tmp[32];
#pragma unroll
        for (int j = 0; j < 32; ++j) tmp[j] = Ah[seg + j][d];
        size_t base = ((size_t)(b * H_ + h) * D_ + d) * L_ + (m0 & 4095) + seg;
#pragma unroll
        for (int c = 0; c < 4; ++c)
            *(u16x8*)(Vw + base + c * 8) = *(u16x8*)&tmp[c * 8];
    }
}

// ---------------------------------------------------------------------------
// Out-projection GEMM, 128x64 tile: A fp16 x Wt fp16 -> C fp32.
// (R4 lesson: fusing the split-K combine here recomputes it per n0-tile
// (8x) and doubles A traffic — net −11 µs. Keep reduce separate.)
// ---------------------------------------------------------------------------
__global__ __launch_bounds__(256) void out_gemm(const u16* __restrict__ A16,
                                                const u16* __restrict__ Wt,
                                                float* __restrict__ Cf) {
    __shared__ u16 As[128][72];
    __shared__ u16 Bs[64][72];
    const int tid = threadIdx.x;
    const int w = tid >> 6, lane = tid & 63, lx = lane & 15, quad = lane >> 4;
    const int m0 = blockIdx.y * 128, n0 = blockIdx.x * 64;

    u16x8 a16p[4];
    u16x8 bp[2];

    auto load_ab = [&](int k0) {
#pragma unroll
        for (int it = 0; it < 4; ++it) {
            int slot = tid + it * 256, r = slot >> 3, g = (slot & 7) * 8;
            a16p[it] = *(const u16x8*)(A16 + (size_t)(m0 + r) * F_ + k0 + g);
        }
#pragma unroll
        for (int it = 0; it < 2; ++it) {
            int slot = tid + it * 256, r = slot >> 3, g = (slot & 7) * 8;
            bp[it] = *(const u16x8*)(Wt + (size_t)(n0 + r) * F_ + k0 + g);
        }
    };
    auto write_ab = [&]() {
#pragma unroll
        for (int it = 0; it < 4; ++it) {
            int slot = tid + it * 256, r = slot >> 3, g = (slot & 7) * 8;
            *(u16x8*)&As[r][g] = a16p[it];
        }
#pragma unroll
        for (int it = 0; it < 2; ++it) {
            int slot = tid + it * 256, r = slot >> 3, g = (slot & 7) * 8;
            *(u16x8*)&Bs[r][g] = bp[it];
        }
    };

    f32x4 acc[2][4] = {};

    load_ab(0);
    write_ab();
    __syncthreads();
    load_ab(64);

    for (int k0 = 0; k0 < F_; k0 += 64) {
#pragma unroll
        for (int ks = 0; ks < 2; ++ks) {
            f16x8 af[2];
#pragma unroll
            for (int mf = 0; mf < 2; ++mf)
                af[mf] = *(const f16x8*)&As[w * 32 + mf * 16 + lx][ks * 32 + quad * 8];
#pragma unroll
            for (int nt = 0; nt < 4; ++nt) {
                f16x8 bf = *(const f16x8*)&Bs[nt * 16 + lx][ks * 32 + quad * 8];
#pragma unroll
                for (int mf = 0; mf < 2; ++mf)
                    acc[mf][nt] = __builtin_amdgcn_mfma_f32_16x16x32_f16(af[mf], bf, acc[mf][nt], 0, 0, 0);
            }
        }
        if (k0 < F_ - 64) {
            __syncthreads();
            write_ab();
            __syncthreads();
            if (k0 < F_ - 128) load_ab(k0 + 128);
        }
    }

#pragma unroll
    for (int mf = 0; mf < 2; ++mf)
#pragma unroll
        for (int nt = 0; nt < 4; ++nt)
#pragma unroll
            for (int i = 0; i < 4; ++i) {
                int m = m0 + w * 32 + mf * 16 + quad * 4 + i;
                int n = n0 + nt * 16 + lx;
                Cf[(size_t)m * F_ + n] = acc[mf][nt][i];
            }
}

// ---------------------------------------------------------------------------
// MFMA flash attention, R7: within-wave ILP restructure.
// R6 established: register footprint (~96 VGPR + ~80 acc in unified file)
// hard-caps residency at 2 waves/SIMD regardless of grid, and extra TLP is
// a null (dur identical at 2x grid) — the wall is in-order-issue dependency
// stalls: the old QK_A->SM_A->PV_A->QK_B->SM_B->PV_B chain splits MFMA work
// into 4 short blocks separated by VALU, so the matrix pipe drains at each
// boundary. New per-kt order:
//   QK_A+QK_B (32 back-to-back MFMA) -> write_kv (DS, overlaps MFMA drain)
//   -> SM_A+SM_B (pure VALU, overlaps other wave's MFMA block)
//   -> PV_A+PV_B (40 back-to-back MFMA)
// Numerics bit-identical: same ops, same accumulation order per o[qf][nt].
// Cost: sv[4][4] + ap0/ap1 both live => ~224 regs, still 2 waves/SIMD cap,
// under the (256,2) 256-reg ceiling. NSPL back to 2 (R6's 4 only bought
// reduce overhead).
// ---------------------------------------------------------------------------
__global__ __launch_bounds__(256, 2) void flash_mfma(
    const u16* __restrict__ Qg, const u16* __restrict__ Kg,
    const u16* __restrict__ Vtg, u16* __restrict__ On, float* __restrict__ Ls) {
    __shared__ u16 Ks[2][64][72];   // fp16, double-buffered
    __shared__ u16 Vs[2][64][72];   // bf16, V^T tile [d][kcol], double-buffered

    const int tid = threadIdx.x;
    const int w = tid >> 6, lane = tid & 63, lx = lane & 15, quad = lane >> 4;

    // decode: 512 = 8 xcd * (2 head * 2 split * 16 qtile)
    const int x = blockIdx.x;
    const int t = x >> 3;
    const int hh = t >> 5;
    const int s = (t >> 4) & 1;
    const int bh = (x & 7) * 2 + hh;
    const int q0 = (t & 15) * 256;

    const u16* Qp = Qg + ((size_t)bh * L_ + q0) * D_;
    const u16* Kp = Kg + (size_t)bh * L_ * D_ + (size_t)(s * KHALF) * D_;
    const u16* Vp = Vtg + (size_t)bh * D_ * L_ + s * KHALF;

    // Q fragments straight to registers (B-operand layout), 64 q-rows/wave
    f16x8 qreg[4][2];
#pragma unroll
    for (int qf = 0; qf < 4; ++qf)
#pragma unroll
        for (int ks = 0; ks < 2; ++ks)
            qreg[qf][ks] = *(const f16x8*)(Qp + (size_t)(w * 64 + qf * 16 + lx) * D_ +
                                           ks * 32 + quad * 8);

    u16x8 kp[2], vp[2];
    auto load_kv = [&](int kt) {
#pragma unroll
        for (int it = 0; it < 2; ++it) {
            int slot = tid + it * 256, r = slot >> 3, g = (slot & 7) * 8;
            kp[it] = *(const u16x8*)(Kp + (size_t)(kt * 64 + r) * D_ + g);
            vp[it] = *(const u16x8*)(Vp + (size_t)r * L_ + kt * 64 + g);
        }
    };
    auto write_kv = [&](int p) {
#pragma unroll
        for (int it = 0; it < 2; ++it) {
            int slot = tid + it * 256, r = slot >> 3, g = (slot & 7) * 8;
            *(u16x8*)&Ks[p][r][g] = kp[it];
            *(u16x8*)&Vs[p][r][g] = vp[it];
        }
    };

    const bf16x8 vone = {0x3F80, 0x3F80, 0x3F80, 0x3F80,
                         0x3F80, 0x3F80, 0x3F80, 0x3F80};  // bf16 1.0 x8
    f32x4 o[4][4] = {};
    f32x4 osum[4] = {};

    load_kv(0);
    write_kv(0);
    __syncthreads();
    load_kv(1);   // in flight during first compute

    const int NT = KHALF / 64;
    for (int kt = 0; kt < NT; ++kt) {
        const int p = kt & 1;

        // ---- QK (both halves): 32 back-to-back MFMAs ---------------------
        // S^T = K Q^T : lane holds S^T[k=nt*16+quad*4+i][q=w*64+qf*16+lx]
        f32x4 sv[4][4] = {};
#pragma unroll
        for (int ks = 0; ks < 2; ++ks)
#pragma unroll
            for (int nt = 0; nt < 4; ++nt) {
                f16x8 ak = *(const f16x8*)&Ks[p][nt * 16 + lx][ks * 32 + quad * 8];
#pragma unroll
                for (int qf = 0; qf < 4; ++qf)
                    sv[nt][qf] = __builtin_amdgcn_mfma_f32_16x16x32_f16(ak, qreg[qf][ks], sv[nt][qf], 0, 0, 0);
            }

        // stage next tile into the other buffer (DS ops overlap MFMA drain;
        // safe: all reads of buf p^1 retired before last iter's barrier)
        if (kt < NT - 1) write_kv(p ^ 1);

        // ---- softmax (both halves), pure VALU — overlaps the other
        //      wave's MFMA blocks; permlane swap keeps P in registers -----
        bf16x8 ap0[4], ap1[4];
#pragma unroll
        for (int half = 0; half < 2; ++half)
#pragma unroll
            for (int qf = 0; qf < 4; ++qf) {
                u32 pu[2], pw[2];
#pragma unroll
                for (int n = 0; n < 2; ++n) {
                    u32 ub[4];
#pragma unroll
                    for (int i = 0; i < 4; ++i)
                        ub[i] = __float_as_uint(__builtin_amdgcn_exp2f(sv[half * 2 + n][qf][i]));
                    pu[n] = __builtin_amdgcn_perm(ub[1], ub[0], 0x07060302u);
                    pw[n] = __builtin_amdgcn_perm(ub[3], ub[2], 0x07060302u);
                }
                u32x2 r  = __builtin_amdgcn_permlane32_swap(pu[0], pu[1], false, false);
                u32x2 r2 = __builtin_amdgcn_permlane16_swap(r[0], r[1], false, false);
                u32x2 tt = __builtin_amdgcn_permlane32_swap(pw[0], pw[1], false, false);
                u32x2 t2 = __builtin_amdgcn_permlane16_swap(tt[0], tt[1], false, false);
                union { u32 d[4]; bf16x8 h; } cvt;
                cvt.d[0] = r2[0];
                cvt.d[1] = t2[0];
                cvt.d[2] = r2[1];
                cvt.d[3] = t2[1];
                if (half == 0) ap0[qf] = cvt.h; else ap1[qf] = cvt.h;
            }

        // ---- PV (both halves): 40 back-to-back MFMAs ---------------------
        __builtin_amdgcn_s_setprio(1);
#pragma unroll
        for (int qf = 0; qf < 4; ++qf)
            osum[qf] = __builtin_amdgcn_mfma_f32_16x16x32_bf16(ap0[qf], vone, osum[qf], 0, 0, 0);
#pragma unroll
        for (int nt = 0; nt < 4; ++nt) {
            bf16x8 bv = *(const bf16x8*)&Vs[p][nt * 16 + lx][quad * 8];
#pragma unroll
            for (int qf = 0; qf < 4; ++qf)
                o[qf][nt] = __builtin_amdgcn_mfma_f32_16x16x32_bf16(ap0[qf], bv, o[qf][nt], 0, 0, 0);
        }
#pragma unroll
        for (int qf = 0; qf < 4; ++qf)
            osum[qf] = __builtin_amdgcn_mfma_f32_16x16x32_bf16(ap1[qf], vone, osum[qf], 0, 0, 0);
#pragma unroll
        for (int nt = 0; nt < 4; ++nt) {
            bf16x8 bv = *(const bf16x8*)&Vs[p][nt * 16 + lx][32 + quad * 8];
#pragma unroll
            for (int qf = 0; qf < 4; ++qf)
                o[qf][nt] = __builtin_amdgcn_mfma_f32_16x16x32_bf16(ap1[qf], bv, o[qf][nt], 0, 0, 0);
        }
        __builtin_amdgcn_s_setprio(0);

        if (kt < NT - 2) load_kv(kt + 2);  // next-next tile into regs
        if (kt < NT - 1) __syncthreads();  // ONE barrier per kt (dbuf)
    }

    // write On = O/l (fp16, [B,L,H*D]) and l (f32)
    const int b = bh >> 3, h = bh & 7;
    u16* Op = On + (size_t)s * M_ * F_;
#pragma unroll
    for (int qf = 0; qf < 4; ++qf) {
        float linv[4];
#pragma unroll
        for (int i = 0; i < 4; ++i) linv[i] = 1.f / osum[qf][i];
#pragma unroll
        for (int nt = 0; nt < 4; ++nt)
#pragma unroll
            for (int i = 0; i < 4; ++i) {
                int l = q0 + w * 64 + qf * 16 + quad * 4 + i;
                Op[((size_t)b * L_ + l) * (H_ * D_) + h * D_ + nt * 16 + lx] =
                    f2h(o[qf][nt][i] * linv[i]);
            }
        if (lx == 0) {
            float* lp = Ls + ((size_t)s * (B_ * H_) + bh) * L_ +
                        q0 + w * 64 + qf * 16 + quad * 4;
#pragma unroll
            for (int i = 0; i < 4; ++i) lp[i] = osum[qf][i];
        }
    }
}

// ---------------------------------------------------------------------------
// Combine split-K partials: O = (l1*O1n + l2*O2n) / (l1+l2).
// ---------------------------------------------------------------------------
__global__ __launch_bounds__(256) void reduce_kernel(
    const u16* __restrict__ On, const float* __restrict__ Ls,
    u16* __restrict__ Ow) {
    int gid = blockIdx.x * 256 + threadIdx.x;  // u16x8 group, grid covers M_*F_/8
    size_t off = (size_t)gid * 8;
    int row = gid >> 3;                        // 64 elems per (b,l,h) row
    int b = row >> 15, rem = row & 32767;
    int l = rem >> 3, h = rem & 7;
    int lidx = ((b * H_ + h) << 12) + l;
    float l1 = Ls[lidx], l2 = Ls[B_ * H_ * L_ + lidx];
    float w1 = l1 / (l1 + l2), w2 = 1.f - w1;
    u16x8 a = *(const u16x8*)(On + off);
    u16x8 c = *(const u16x8*)(On + (size_t)M_ * F_ + off);
    u16 r[8];
#pragma unroll
    for (int j = 0; j < 8; ++j)
        r[j] = f2h(w1 * h2f(a[j]) + w2 * h2f(c[j]));
    *(u16x8*)(Ow + off) = *(u16x8*)r;
}

// ---------------------------------------------------------------------------
extern "C" void kernel_launch(void* const* d_in, const int* in_sizes, int n_in,
                              void* d_out, int out_size, void* d_ws, size_t ws_size,
                              hipStream_t stream)
{
    const float* Xq  = (const float*)d_in[0];
    const float* Xkv = (const float*)d_in[1];
    const float* Wq  = (const float*)d_in[2];
    const float* Wk  = (const float*)d_in[3];
    const float* Wv  = (const float*)d_in[4];
    const float* Wo  = (const float*)d_in[5];
    float* out = (float*)d_out;

    u16* ws  = (u16*)d_ws;
    const size_t MF = (size_t)M_ * F_;
    const size_t FF = (size_t)F_ * F_;
    u16* Wqt = ws;             // W^T 512x512 fp16 each
    u16* Wkt = Wqt + FF;
    u16* Wvt = Wkt + FF;
    u16* Wot = Wvt + FF;
    u16* Qw  = Wot + FF;       // [B,H,L,D] fp16, pre-scaled by log2e
    u16* Kw  = Qw + MF;        // [B,H,L,D] fp16
    u16* Vw  = Kw + MF;        // [B,H,D,L] bf16
    u16* On  = Vw + MF;        // 2 x [B,L,H*D] fp16 split partials
    float* Ls = (float*)(On + 2 * MF);  // 2 x [BH, L] f32
    u16* Ow  = Qw;             // reduced O aliases Qw (dead after flash)

    wt_kernel<<<dim3(16, 16, 4), 256, 0, stream>>>(Wq, Wk, Wv, Wo,
                                                   Wqt, Wkt, Wvt, Wot);

    proj_kernel<<<dim3(8, 64, 2), 256, 0, stream>>>(Xq, Xkv, Wqt, Wkt, Wvt,
                                                    Qw, Kw, Vw);

    flash_mfma<<<dim3(512), 256, 0, stream>>>(Qw, Kw, Vw, On, Ls);

    reduce_kernel<<<dim3((int)(MF / 8 / 256)), 256, 0, stream>>>(On, Ls, Ow);

    out_gemm<<<dim3(8, 64), 256, 0, stream>>>(Ow, Wot, out);
}

// Round 8
// 215.519 us; speedup vs baseline: 2.8521x; 1.0027x over previous
//
#include <hip/hip_runtime.h>
#include <hip/hip_bf16.h>

typedef short bf16x8 __attribute__((ext_vector_type(8)));
typedef _Float16 f16;
typedef f16 f16x8 __attribute__((ext_vector_type(8)));
typedef float f32x4 __attribute__((ext_vector_type(4)));
typedef unsigned short u16;
typedef u16 u16x8 __attribute__((ext_vector_type(8)));
typedef unsigned int u32;
typedef u32 u32x2 __attribute__((ext_vector_type(2)));

#define B_  2
#define L_  4096
#define F_  512
#define H_  8
#define D_  64
#define M_  8192       // B_*L_
#define NSPL 2         // flash split-K factor
#define KHALF (L_ / NSPL)

#define LOG2E 1.442695041f

__device__ inline u16 f2bf(float f) {
    union { float f; unsigned u; } v; v.f = f;
    unsigned r = v.u + 0x7fff + ((v.u >> 16) & 1);  // RNE
    return (u16)(r >> 16);
}
__device__ inline u16 f2h(float f) {
    union { f16 h; u16 u; } v; v.h = (f16)f;  // RNE hw cvt
    return v.u;
}
__device__ inline float h2f(u16 u) {
    union { u16 u; f16 h; } v; v.u = u;
    return (float)v.h;
}

// ---------------------------------------------------------------------------
// Fused weight transpose: W [512 k][512 n] fp32 -> Wt [512 n][512 k] fp16.
// ---------------------------------------------------------------------------
__global__ __launch_bounds__(256) void wt_kernel(
    const float* __restrict__ Wq, const float* __restrict__ Wk,
    const float* __restrict__ Wv, const float* __restrict__ Wo,
    u16* __restrict__ Tq, u16* __restrict__ Tk,
    u16* __restrict__ Tv, u16* __restrict__ To) {
    __shared__ float t[32][33];
    const int z = blockIdx.z;
    const float* in = (z == 0) ? Wq : (z == 1) ? Wk : (z == 2) ? Wv : Wo;
    u16* out = (z == 0) ? Tq : (z == 1) ? Tk : (z == 2) ? Tv : To;
    int k0 = blockIdx.y * 32, n0 = blockIdx.x * 32;
    int c = threadIdx.x & 31, r8 = threadIdx.x >> 5;
#pragma unroll
    for (int i = 0; i < 4; ++i) {
        int r = r8 * 4 + i;
        t[r][c] = in[(size_t)(k0 + r) * F_ + n0 + c];
    }
    __syncthreads();
#pragma unroll
    for (int i = 0; i < 4; ++i) {
        int r = r8 * 4 + i;
        out[(size_t)(n0 + r) * F_ + k0 + c] = f2h(t[c][r]);
    }
}

// ---------------------------------------------------------------------------
// Fused projection kernel, 128x64 tile, register prefetch (loads issued
// AFTER the barrier pair so no barrier drains a fresh vmcnt).
// z=0: Q = Xq*Wq (scaled log2e) -> [B,H,L,D] fp16.
// z=1: K -> [B,H,L,D] fp16;  V -> [B,H,D,L] bf16 transposed.
// ---------------------------------------------------------------------------
__global__ __launch_bounds__(256, 3) void proj_kernel(
    const float* __restrict__ Xq, const float* __restrict__ Xkv,
    const u16* __restrict__ Wqt, const u16* __restrict__ Wkt,
    const u16* __restrict__ Wvt,
    u16* __restrict__ Qw, u16* __restrict__ Kw, u16* __restrict__ Vw) {
    __shared__ u16 Ah[128][72];
    __shared__ u16 B1[64][72];
    __shared__ u16 B2[64][72];
    const int tid = threadIdx.x;
    const int w = tid >> 6, lane = tid & 63, lx = lane & 15, quad = lane >> 4;
    const int m0 = blockIdx.y * 128, n0 = blockIdx.x * 64;
    const bool isKV = (blockIdx.z == 1);
    const float* A = isKV ? Xkv : Xq;
    const u16* W1 = isKV ? Wkt : Wqt;

    float4 apre[8];
    u16x8 b1p[2], b2p[2];

    auto load_ab = [&](int k0) {
#pragma unroll
        for (int it = 0; it < 4; ++it) {
            int slot = tid + it * 256, r = slot >> 3, g = (slot & 7) * 8;
            apre[2 * it]     = *(const float4*)(A + (size_t)(m0 + r) * F_ + k0 + g);
            apre[2 * it + 1] = *(const float4*)(A + (size_t)(m0 + r) * F_ + k0 + g + 4);
        }
#pragma unroll
        for (int it = 0; it < 2; ++it) {
            int slot = tid + it * 256, r = slot >> 3, g = (slot & 7) * 8;
            b1p[it] = *(const u16x8*)(W1 + (size_t)(n0 + r) * F_ + k0 + g);
            if (isKV)
                b2p[it] = *(const u16x8*)(Wvt + (size_t)(n0 + r) * F_ + k0 + g);
        }
    };
    auto write_ab = [&]() {
#pragma unroll
        for (int it = 0; it < 4; ++it) {
            int slot = tid + it * 256, r = slot >> 3, g = (slot & 7) * 8;
            float4 f0 = apre[2 * it], f1 = apre[2 * it + 1];
            u16 th[8] = {f2h(f0.x), f2h(f0.y), f2h(f0.z), f2h(f0.w),
                         f2h(f1.x), f2h(f1.y), f2h(f1.z), f2h(f1.w)};
            *(u16x8*)&Ah[r][g] = *(u16x8*)th;
        }
#pragma unroll
        for (int it = 0; it < 2; ++it) {
            int slot = tid + it * 256, r = slot >> 3, g = (slot & 7) * 8;
            *(u16x8*)&B1[r][g] = b1p[it];
            if (isKV) *(u16x8*)&B2[r][g] = b2p[it];
        }
    };

    f32x4 acc1[2][4] = {}, acc2[2][4] = {};

    load_ab(0);
    write_ab();
    __syncthreads();
    load_ab(64);   // in flight during first compute

    for (int k0 = 0; k0 < F_; k0 += 64) {
#pragma unroll
        for (int ks = 0; ks < 2; ++ks) {
            f16x8 af[2];
#pragma unroll
            for (int mf = 0; mf < 2; ++mf)
                af[mf] = *(const f16x8*)&Ah[w * 32 + mf * 16 + lx][ks * 32 + quad * 8];
#pragma unroll
            for (int nt = 0; nt < 4; ++nt) {
                f16x8 b1 = *(const f16x8*)&B1[nt * 16 + lx][ks * 32 + quad * 8];
#pragma unroll
                for (int mf = 0; mf < 2; ++mf)
                    acc1[mf][nt] = __builtin_amdgcn_mfma_f32_16x16x32_f16(af[mf], b1, acc1[mf][nt], 0, 0, 0);
                if (isKV) {
                    f16x8 b2 = *(const f16x8*)&B2[nt * 16 + lx][ks * 32 + quad * 8];
#pragma unroll
                    for (int mf = 0; mf < 2; ++mf)
                        acc2[mf][nt] = __builtin_amdgcn_mfma_f32_16x16x32_f16(af[mf], b2, acc2[mf][nt], 0, 0, 0);
                }
            }
        }
        if (k0 < F_ - 64) {
            __syncthreads();   // loads for k0+64 landed during this compute
            write_ab();
            __syncthreads();
            if (k0 < F_ - 128) load_ab(k0 + 128);  // issued AFTER barriers
        }
    }

    const int h = n0 >> 6;
    const float scl = isKV ? 1.0f : LOG2E;
    u16* C1 = isKV ? Kw : Qw;
#pragma unroll
    for (int mf = 0; mf < 2; ++mf)
#pragma unroll
        for (int nt = 0; nt < 4; ++nt)
#pragma unroll
            for (int i = 0; i < 4; ++i) {
                int m = m0 + w * 32 + mf * 16 + quad * 4 + i;
                int b = m >> 12, l = m & 4095;
                int d = nt * 16 + lx;
                C1[((size_t)(b * H_ + h) * L_ + l) * D_ + d] = f2h(acc1[mf][nt][i] * scl);
            }
    if (isKV) {
        __syncthreads();
#pragma unroll
        for (int mf = 0; mf < 2; ++mf)
#pragma unroll
            for (int nt = 0; nt < 4; ++nt)
#pragma unroll
                for (int i = 0; i < 4; ++i)
                    Ah[w * 32 + mf * 16 + quad * 4 + i][nt * 16 + lx] = f2bf(acc2[mf][nt][i]);
        __syncthreads();
        int d = tid >> 2, seg = (tid & 3) * 32;
        int b = m0 >> 12;
        u16 tmp[32];
#pragma unroll
        for (int j = 0; j < 32; ++j) tmp[j] = Ah[seg + j][d];
        size_t base = ((size_t)(b * H_ + h) * D_ + d) * L_ + (m0 & 4095) + seg;
#pragma unroll
        for (int c = 0; c < 4; ++c)
            *(u16x8*)(Vw + base + c * 8) = *(u16x8*)&tmp[c * 8];
    }
}

// ---------------------------------------------------------------------------
// Out-projection GEMM, R8: 128x128 tile (grid 4x64) — halves B traffic and
// doubles the MFMA:LDS-read ratio vs the old 128x64 tile.
// acc[2][8], ~130 VGPR, 36 KB LDS, 2 blocks/CU.
// ---------------------------------------------------------------------------
__global__ __launch_bounds__(256) void out_gemm(const u16* __restrict__ A16,
                                                const u16* __restrict__ Wt,
                                                float* __restrict__ Cf) {
    __shared__ u16 As[128][72];
    __shared__ u16 Bs[128][72];
    const int tid = threadIdx.x;
    const int w = tid >> 6, lane = tid & 63, lx = lane & 15, quad = lane >> 4;
    const int m0 = blockIdx.y * 128, n0 = blockIdx.x * 128;

    u16x8 a16p[4];
    u16x8 bp[4];

    auto load_ab = [&](int k0) {
#pragma unroll
        for (int it = 0; it < 4; ++it) {
            int slot = tid + it * 256, r = slot >> 3, g = (slot & 7) * 8;
            a16p[it] = *(const u16x8*)(A16 + (size_t)(m0 + r) * F_ + k0 + g);
            bp[it]   = *(const u16x8*)(Wt  + (size_t)(n0 + r) * F_ + k0 + g);
        }
    };
    auto write_ab = [&]() {
#pragma unroll
        for (int it = 0; it < 4; ++it) {
            int slot = tid + it * 256, r = slot >> 3, g = (slot & 7) * 8;
            *(u16x8*)&As[r][g] = a16p[it];
            *(u16x8*)&Bs[r][g] = bp[it];
        }
    };

    f32x4 acc[2][8] = {};

    load_ab(0);
    write_ab();
    __syncthreads();
    load_ab(64);

    for (int k0 = 0; k0 < F_; k0 += 64) {
#pragma unroll
        for (int ks = 0; ks < 2; ++ks) {
            f16x8 af[2];
#pragma unroll
            for (int mf = 0; mf < 2; ++mf)
                af[mf] = *(const f16x8*)&As[w * 32 + mf * 16 + lx][ks * 32 + quad * 8];
#pragma unroll
            for (int nt = 0; nt < 8; ++nt) {
                f16x8 bf = *(const f16x8*)&Bs[nt * 16 + lx][ks * 32 + quad * 8];
#pragma unroll
                for (int mf = 0; mf < 2; ++mf)
                    acc[mf][nt] = __builtin_amdgcn_mfma_f32_16x16x32_f16(af[mf], bf, acc[mf][nt], 0, 0, 0);
            }
        }
        if (k0 < F_ - 64) {
            __syncthreads();
            write_ab();
            __syncthreads();
            if (k0 < F_ - 128) load_ab(k0 + 128);
        }
    }

#pragma unroll
    for (int mf = 0; mf < 2; ++mf)
#pragma unroll
        for (int nt = 0; nt < 8; ++nt)
#pragma unroll
            for (int i = 0; i < 4; ++i) {
                int m = m0 + w * 32 + mf * 16 + quad * 4 + i;
                int n = n0 + nt * 16 + lx;
                Cf[(size_t)m * F_ + n] = acc[mf][nt][i];
            }
}

// ---------------------------------------------------------------------------
// MFMA flash attention, R8: R7 structure + prefetch moved AFTER the barrier.
// R7 diagnosis: ~45% of SIMD cycles issue nothing; the common per-kt stall
// is load_kv(kt+2) issued immediately BEFORE __syncthreads() — the barrier's
// compiler-mandated s_waitcnt vmcnt(0) drains the just-issued global loads
// (L2 ~200-300 cyc each kt, all waves). Moving the load after the barrier
// means the barrier only drains loads issued a full kt earlier (complete)
// plus the LDS writes it must drain anyway. Dbuf invariant unchanged:
// write_kv(p^1) before barrier, reads of p^1 after.
// Per-kt order (R7 ILP form): QK_A+B (32 MFMA) -> write_kv -> SM_A+B (VALU)
// -> PV_A+B (40 MFMA) -> barrier -> load_kv(kt+2).
// ---------------------------------------------------------------------------
__global__ __launch_bounds__(256, 2) void flash_mfma(
    const u16* __restrict__ Qg, const u16* __restrict__ Kg,
    const u16* __restrict__ Vtg, u16* __restrict__ On, float* __restrict__ Ls) {
    __shared__ u16 Ks[2][64][72];   // fp16, double-buffered
    __shared__ u16 Vs[2][64][72];   // bf16, V^T tile [d][kcol], double-buffered

    const int tid = threadIdx.x;
    const int w = tid >> 6, lane = tid & 63, lx = lane & 15, quad = lane >> 4;

    // decode: 512 = 8 xcd * (2 head * 2 split * 16 qtile)
    const int x = blockIdx.x;
    const int t = x >> 3;
    const int hh = t >> 5;
    const int s = (t >> 4) & 1;
    const int bh = (x & 7) * 2 + hh;
    const int q0 = (t & 15) * 256;

    const u16* Qp = Qg + ((size_t)bh * L_ + q0) * D_;
    const u16* Kp = Kg + (size_t)bh * L_ * D_ + (size_t)(s * KHALF) * D_;
    const u16* Vp = Vtg + (size_t)bh * D_ * L_ + s * KHALF;

    // Q fragments straight to registers (B-operand layout), 64 q-rows/wave
    f16x8 qreg[4][2];
#pragma unroll
    for (int qf = 0; qf < 4; ++qf)
#pragma unroll
        for (int ks = 0; ks < 2; ++ks)
            qreg[qf][ks] = *(const f16x8*)(Qp + (size_t)(w * 64 + qf * 16 + lx) * D_ +
                                           ks * 32 + quad * 8);

    u16x8 kp[2], vp[2];
    auto load_kv = [&](int kt) {
#pragma unroll
        for (int it = 0; it < 2; ++it) {
            int slot = tid + it * 256, r = slot >> 3, g = (slot & 7) * 8;
            kp[it] = *(const u16x8*)(Kp + (size_t)(kt * 64 + r) * D_ + g);
            vp[it] = *(const u16x8*)(Vp + (size_t)r * L_ + kt * 64 + g);
        }
    };
    auto write_kv = [&](int p) {
#pragma unroll
        for (int it = 0; it < 2; ++it) {
            int slot = tid + it * 256, r = slot >> 3, g = (slot & 7) * 8;
            *(u16x8*)&Ks[p][r][g] = kp[it];
            *(u16x8*)&Vs[p][r][g] = vp[it];
        }
    };

    const bf16x8 vone = {0x3F80, 0x3F80, 0x3F80, 0x3F80,
                         0x3F80, 0x3F80, 0x3F80, 0x3F80};  // bf16 1.0 x8
    f32x4 o[4][4] = {};
    f32x4 osum[4] = {};

    load_kv(0);
    write_kv(0);
    __syncthreads();
    load_kv(1);   // in flight during first compute

    const int NT = KHALF / 64;
    for (int kt = 0; kt < NT; ++kt) {
        const int p = kt & 1;

        // ---- QK (both halves): 32 back-to-back MFMAs ---------------------
        // S^T = K Q^T : lane holds S^T[k=nt*16+quad*4+i][q=w*64+qf*16+lx]
        f32x4 sv[4][4] = {};
#pragma unroll
        for (int ks = 0; ks < 2; ++ks)
#pragma unroll
            for (int nt = 0; nt < 4; ++nt) {
                f16x8 ak = *(const f16x8*)&Ks[p][nt * 16 + lx][ks * 32 + quad * 8];
#pragma unroll
                for (int qf = 0; qf < 4; ++qf)
                    sv[nt][qf] = __builtin_amdgcn_mfma_f32_16x16x32_f16(ak, qreg[qf][ks], sv[nt][qf], 0, 0, 0);
            }

        // stage next tile into the other buffer (regs loaded ≥1 kt ago ->
        // the implicit vmcnt wait here is fully covered by QK)
        if (kt < NT - 1) write_kv(p ^ 1);

        // ---- softmax (both halves), pure VALU — overlaps the other
        //      wave's MFMA blocks; permlane swap keeps P in registers -----
        bf16x8 ap0[4], ap1[4];
#pragma unroll
        for (int half = 0; half < 2; ++half)
#pragma unroll
            for (int qf = 0; qf < 4; ++qf) {
                u32 pu[2], pw[2];
#pragma unroll
                for (int n = 0; n < 2; ++n) {
                    u32 ub[4];
#pragma unroll
                    for (int i = 0; i < 4; ++i)
                        ub[i] = __float_as_uint(__builtin_amdgcn_exp2f(sv[half * 2 + n][qf][i]));
                    pu[n] = __builtin_amdgcn_perm(ub[1], ub[0], 0x07060302u);
                    pw[n] = __builtin_amdgcn_perm(ub[3], ub[2], 0x07060302u);
                }
                u32x2 r  = __builtin_amdgcn_permlane32_swap(pu[0], pu[1], false, false);
                u32x2 r2 = __builtin_amdgcn_permlane16_swap(r[0], r[1], false, false);
                u32x2 tt = __builtin_amdgcn_permlane32_swap(pw[0], pw[1], false, false);
                u32x2 t2 = __builtin_amdgcn_permlane16_swap(tt[0], tt[1], false, false);
                union { u32 d[4]; bf16x8 h; } cvt;
                cvt.d[0] = r2[0];
                cvt.d[1] = t2[0];
                cvt.d[2] = r2[1];
                cvt.d[3] = t2[1];
                if (half == 0) ap0[qf] = cvt.h; else ap1[qf] = cvt.h;
            }

        // ---- PV (both halves): 40 back-to-back MFMAs ---------------------
        __builtin_amdgcn_s_setprio(1);
#pragma unroll
        for (int qf = 0; qf < 4; ++qf)
            osum[qf] = __builtin_amdgcn_mfma_f32_16x16x32_bf16(ap0[qf], vone, osum[qf], 0, 0, 0);
#pragma unroll
        for (int nt = 0; nt < 4; ++nt) {
            bf16x8 bv = *(const bf16x8*)&Vs[p][nt * 16 + lx][quad * 8];
#pragma unroll
            for (int qf = 0; qf < 4; ++qf)
                o[qf][nt] = __builtin_amdgcn_mfma_f32_16x16x32_bf16(ap0[qf], bv, o[qf][nt], 0, 0, 0);
        }
#pragma unroll
        for (int qf = 0; qf < 4; ++qf)
            osum[qf] = __builtin_amdgcn_mfma_f32_16x16x32_bf16(ap1[qf], vone, osum[qf], 0, 0, 0);
#pragma unroll
        for (int nt = 0; nt < 4; ++nt) {
            bf16x8 bv = *(const bf16x8*)&Vs[p][nt * 16 + lx][32 + quad * 8];
#pragma unroll
            for (int qf = 0; qf < 4; ++qf)
                o[qf][nt] = __builtin_amdgcn_mfma_f32_16x16x32_bf16(ap1[qf], bv, o[qf][nt], 0, 0, 0);
        }
        __builtin_amdgcn_s_setprio(0);

        if (kt < NT - 1) __syncthreads();  // drains LDS writes + OLD loads only
        if (kt < NT - 2) load_kv(kt + 2);  // issued AFTER the barrier:
                                           // no barrier drains a fresh vmcnt
    }

    // write On = O/l (fp16, [B,L,H*D]) and l (f32)
    const int b = bh >> 3, h = bh & 7;
    u16* Op = On + (size_t)s * M_ * F_;
#pragma unroll
    for (int qf = 0; qf < 4; ++qf) {
        float linv[4];
#pragma unroll
        for (int i = 0; i < 4; ++i) linv[i] = 1.f / osum[qf][i];
#pragma unroll
        for (int nt = 0; nt < 4; ++nt)
#pragma unroll
            for (int i = 0; i < 4; ++i) {
                int l = q0 + w * 64 + qf * 16 + quad * 4 + i;
                Op[((size_t)b * L_ + l) * (H_ * D_) + h * D_ + nt * 16 + lx] =
                    f2h(o[qf][nt][i] * linv[i]);
            }
        if (lx == 0) {
            float* lp = Ls + ((size_t)s * (B_ * H_) + bh) * L_ +
                        q0 + w * 64 + qf * 16 + quad * 4;
#pragma unroll
            for (int i = 0; i < 4; ++i) lp[i] = osum[qf][i];
        }
    }
}

// ---------------------------------------------------------------------------
// Combine split-K partials: O = (l1*O1n + l2*O2n) / (l1+l2).
// ---------------------------------------------------------------------------
__global__ __launch_bounds__(256) void reduce_kernel(
    const u16* __restrict__ On, const float* __restrict__ Ls,
    u16* __restrict__ Ow) {
    int gid = blockIdx.x * 256 + threadIdx.x;  // u16x8 group, grid covers M_*F_/8
    size_t off = (size_t)gid * 8;
    int row = gid >> 3;                        // 64 elems per (b,l,h) row
    int b = row >> 15, rem = row & 32767;
    int l = rem >> 3, h = rem & 7;
    int lidx = ((b * H_ + h) << 12) + l;
    float l1 = Ls[lidx], l2 = Ls[B_ * H_ * L_ + lidx];
    float w1 = l1 / (l1 + l2), w2 = 1.f - w1;
    u16x8 a = *(const u16x8*)(On + off);
    u16x8 c = *(const u16x8*)(On + (size_t)M_ * F_ + off);
    u16 r[8];
#pragma unroll
    for (int j = 0; j < 8; ++j)
        r[j] = f2h(w1 * h2f(a[j]) + w2 * h2f(c[j]));
    *(u16x8*)(Ow + off) = *(u16x8*)r;
}

// ---------------------------------------------------------------------------
extern "C" void kernel_launch(void* const* d_in, const int* in_sizes, int n_in,
                              void* d_out, int out_size, void* d_ws, size_t ws_size,
                              hipStream_t stream)
{
    const float* Xq  = (const float*)d_in[0];
    const float* Xkv = (const float*)d_in[1];
    const float* Wq  = (const float*)d_in[2];
    const float* Wk  = (const float*)d_in[3];
    const float* Wv  = (const float*)d_in[4];
    const float* Wo  = (const float*)d_in[5];
    float* out = (float*)d_out;

    u16* ws  = (u16*)d_ws;
    const size_t MF = (size_t)M_ * F_;
    const size_t FF = (size_t)F_ * F_;
    u16* Wqt = ws;             // W^T 512x512 fp16 each
    u16* Wkt = Wqt + FF;
    u16* Wvt = Wkt + FF;
    u16* Wot = Wvt + FF;
    u16* Qw  = Wot + FF;       // [B,H,L,D] fp16, pre-scaled by log2e
    u16* Kw  = Qw + MF;        // [B,H,L,D] fp16
    u16* Vw  = Kw + MF;        // [B,H,D,L] bf16
    u16* On  = Vw + MF;        // 2 x [B,L,H*D] fp16 split partials
    float* Ls = (float*)(On + 2 * MF);  // 2 x [BH, L] f32
    u16* Ow  = Qw;             // reduced O aliases Qw (dead after flash)

    wt_kernel<<<dim3(16, 16, 4), 256, 0, stream>>>(Wq, Wk, Wv, Wo,
                                                   Wqt, Wkt, Wvt, Wot);

    proj_kernel<<<dim3(8, 64, 2), 256, 0, stream>>>(Xq, Xkv, Wqt, Wkt, Wvt,
                                                    Qw, Kw, Vw);

    flash_mfma<<<dim3(512), 256, 0, stream>>>(Qw, Kw, Vw, On, Ls);

    reduce_kernel<<<dim3((int)(MF / 8 / 256)), 256, 0, stream>>>(On, Ls, Ow);

    out_gemm<<<dim3(4, 64), 256, 0, stream>>>(Ow, Wot, out);
}

// Round 9
// 200.378 us; speedup vs baseline: 3.0676x; 1.0756x over previous
//
#include <hip/hip_runtime.h>
#include <hip/hip_bf16.h>

typedef short bf16x8 __attribute__((ext_vector_type(8)));
typedef _Float16 f16;
typedef f16 f16x8 __attribute__((ext_vector_type(8)));
typedef float f32x4 __attribute__((ext_vector_type(4)));
typedef unsigned short u16;
typedef u16 u16x8 __attribute__((ext_vector_type(8)));
typedef unsigned int u32;
typedef u32 u32x2 __attribute__((ext_vector_type(2)));

#define B_  2
#define L_  4096
#define F_  512
#define H_  8
#define D_  64
#define M_  8192       // B_*L_
#define NSPL 2         // flash split-K factor
#define KHALF (L_ / NSPL)

#define LOG2E 1.442695041f

__device__ inline u16 f2bf(float f) {
    union { float f; unsigned u; } v; v.f = f;
    unsigned r = v.u + 0x7fff + ((v.u >> 16) & 1);  // RNE
    return (u16)(r >> 16);
}
__device__ inline u16 f2h(float f) {
    union { f16 h; u16 u; } v; v.h = (f16)f;  // RNE hw cvt
    return v.u;
}
__device__ inline float h2f(u16 u) {
    union { u16 u; f16 h; } v; v.u = u;
    return (float)v.h;
}

// ---------------------------------------------------------------------------
// Fused weight transpose: W [512 k][512 n] fp32 -> Wt [512 n][512 k] fp16.
// ---------------------------------------------------------------------------
__global__ __launch_bounds__(256) void wt_kernel(
    const float* __restrict__ Wq, const float* __restrict__ Wk,
    const float* __restrict__ Wv, const float* __restrict__ Wo,
    u16* __restrict__ Tq, u16* __restrict__ Tk,
    u16* __restrict__ Tv, u16* __restrict__ To) {
    __shared__ float t[32][33];
    const int z = blockIdx.z;
    const float* in = (z == 0) ? Wq : (z == 1) ? Wk : (z == 2) ? Wv : Wo;
    u16* out = (z == 0) ? Tq : (z == 1) ? Tk : (z == 2) ? Tv : To;
    int k0 = blockIdx.y * 32, n0 = blockIdx.x * 32;
    int c = threadIdx.x & 31, r8 = threadIdx.x >> 5;
#pragma unroll
    for (int i = 0; i < 4; ++i) {
        int r = r8 * 4 + i;
        t[r][c] = in[(size_t)(k0 + r) * F_ + n0 + c];
    }
    __syncthreads();
#pragma unroll
    for (int i = 0; i < 4; ++i) {
        int r = r8 * 4 + i;
        out[(size_t)(n0 + r) * F_ + k0 + c] = f2h(t[c][r]);
    }
}

// ---------------------------------------------------------------------------
// Fused projection kernel, 128x64 tile, register prefetch.
// R9: grid swapped to (64 m-tiles, 8 n-tiles, 2) — with gridDim.x = 8 the
// XCD id equalled the n-tile, so each XCD's A working set was ALL of
// Xq+Xkv (33.6 MB fp32 vs 4 MB L2): aggregate A re-fetch ~268 MB/dispatch.
// With blockIdx.x = m-tile, XCD = m%8 owns 8 m-tiles (2+2 MB A panel),
// reused across all n and z from its own L2 (T1 mechanism, zero numerics).
// z=0: Q = Xq*Wq (scaled log2e) -> [B,H,L,D] fp16.
// z=1: K -> [B,H,L,D] fp16;  V -> [B,H,D,L] bf16 transposed.
// ---------------------------------------------------------------------------
__global__ __launch_bounds__(256, 3) void proj_kernel(
    const float* __restrict__ Xq, const float* __restrict__ Xkv,
    const u16* __restrict__ Wqt, const u16* __restrict__ Wkt,
    const u16* __restrict__ Wvt,
    u16* __restrict__ Qw, u16* __restrict__ Kw, u16* __restrict__ Vw) {
    __shared__ u16 Ah[128][72];
    __shared__ u16 B1[64][72];
    __shared__ u16 B2[64][72];
    const int tid = threadIdx.x;
    const int w = tid >> 6, lane = tid & 63, lx = lane & 15, quad = lane >> 4;
    const int m0 = blockIdx.x * 128, n0 = blockIdx.y * 64;   // R9 swap
    const bool isKV = (blockIdx.z == 1);
    const float* A = isKV ? Xkv : Xq;
    const u16* W1 = isKV ? Wkt : Wqt;

    float4 apre[8];
    u16x8 b1p[2], b2p[2];

    auto load_ab = [&](int k0) {
#pragma unroll
        for (int it = 0; it < 4; ++it) {
            int slot = tid + it * 256, r = slot >> 3, g = (slot & 7) * 8;
            apre[2 * it]     = *(const float4*)(A + (size_t)(m0 + r) * F_ + k0 + g);
            apre[2 * it + 1] = *(const float4*)(A + (size_t)(m0 + r) * F_ + k0 + g + 4);
        }
#pragma unroll
        for (int it = 0; it < 2; ++it) {
            int slot = tid + it * 256, r = slot >> 3, g = (slot & 7) * 8;
            b1p[it] = *(const u16x8*)(W1 + (size_t)(n0 + r) * F_ + k0 + g);
            if (isKV)
                b2p[it] = *(const u16x8*)(Wvt + (size_t)(n0 + r) * F_ + k0 + g);
        }
    };
    auto write_ab = [&]() {
#pragma unroll
        for (int it = 0; it < 4; ++it) {
            int slot = tid + it * 256, r = slot >> 3, g = (slot & 7) * 8;
            float4 f0 = apre[2 * it], f1 = apre[2 * it + 1];
            u16 th[8] = {f2h(f0.x), f2h(f0.y), f2h(f0.z), f2h(f0.w),
                         f2h(f1.x), f2h(f1.y), f2h(f1.z), f2h(f1.w)};
            *(u16x8*)&Ah[r][g] = *(u16x8*)th;
        }
#pragma unroll
        for (int it = 0; it < 2; ++it) {
            int slot = tid + it * 256, r = slot >> 3, g = (slot & 7) * 8;
            *(u16x8*)&B1[r][g] = b1p[it];
            if (isKV) *(u16x8*)&B2[r][g] = b2p[it];
        }
    };

    f32x4 acc1[2][4] = {}, acc2[2][4] = {};

    load_ab(0);
    write_ab();
    __syncthreads();
    load_ab(64);   // in flight during first compute

    for (int k0 = 0; k0 < F_; k0 += 64) {
#pragma unroll
        for (int ks = 0; ks < 2; ++ks) {
            f16x8 af[2];
#pragma unroll
            for (int mf = 0; mf < 2; ++mf)
                af[mf] = *(const f16x8*)&Ah[w * 32 + mf * 16 + lx][ks * 32 + quad * 8];
#pragma unroll
            for (int nt = 0; nt < 4; ++nt) {
                f16x8 b1 = *(const f16x8*)&B1[nt * 16 + lx][ks * 32 + quad * 8];
#pragma unroll
                for (int mf = 0; mf < 2; ++mf)
                    acc1[mf][nt] = __builtin_amdgcn_mfma_f32_16x16x32_f16(af[mf], b1, acc1[mf][nt], 0, 0, 0);
                if (isKV) {
                    f16x8 b2 = *(const f16x8*)&B2[nt * 16 + lx][ks * 32 + quad * 8];
#pragma unroll
                    for (int mf = 0; mf < 2; ++mf)
                        acc2[mf][nt] = __builtin_amdgcn_mfma_f32_16x16x32_f16(af[mf], b2, acc2[mf][nt], 0, 0, 0);
                }
            }
        }
        if (k0 < F_ - 64) {
            __syncthreads();   // loads for k0+64 landed during this compute
            write_ab();
            __syncthreads();
            if (k0 < F_ - 128) load_ab(k0 + 128);  // issued AFTER barriers
        }
    }

    const int h = n0 >> 6;
    const float scl = isKV ? 1.0f : LOG2E;
    u16* C1 = isKV ? Kw : Qw;
#pragma unroll
    for (int mf = 0; mf < 2; ++mf)
#pragma unroll
        for (int nt = 0; nt < 4; ++nt)
#pragma unroll
            for (int i = 0; i < 4; ++i) {
                int m = m0 + w * 32 + mf * 16 + quad * 4 + i;
                int b = m >> 12, l = m & 4095;
                int d = nt * 16 + lx;
                C1[((size_t)(b * H_ + h) * L_ + l) * D_ + d] = f2h(acc1[mf][nt][i] * scl);
            }
    if (isKV) {
        __syncthreads();
#pragma unroll
        for (int mf = 0; mf < 2; ++mf)
#pragma unroll
            for (int nt = 0; nt < 4; ++nt)
#pragma unroll
                for (int i = 0; i < 4; ++i)
                    Ah[w * 32 + mf * 16 + quad * 4 + i][nt * 16 + lx] = f2bf(acc2[mf][nt][i]);
        __syncthreads();
        int d = tid >> 2, seg = (tid & 3) * 32;
        int b = m0 >> 12;
        u16 tmp[32];
#pragma unroll
        for (int j = 0; j < 32; ++j) tmp[j] = Ah[seg + j][d];
        size_t base = ((size_t)(b * H_ + h) * D_ + d) * L_ + (m0 & 4095) + seg;
#pragma unroll
        for (int c = 0; c < 4; ++c)
            *(u16x8*)(Vw + base + c * 8) = *(u16x8*)&tmp[c * 8];
    }
}

// ---------------------------------------------------------------------------
// Out-projection GEMM, 128x128 tile. R9: grid (64 m, 4 n) so XCD = m%8
// owns a 1 MB A-panel (was (4,64): XCD=(n+4m)%8, scattered panel).
// ---------------------------------------------------------------------------
__global__ __launch_bounds__(256) void out_gemm(const u16* __restrict__ A16,
                                                const u16* __restrict__ Wt,
                                                float* __restrict__ Cf) {
    __shared__ u16 As[128][72];
    __shared__ u16 Bs[128][72];
    const int tid = threadIdx.x;
    const int w = tid >> 6, lane = tid & 63, lx = lane & 15, quad = lane >> 4;
    const int m0 = blockIdx.x * 128, n0 = blockIdx.y * 128;  // R9 swap

    u16x8 a16p[4];
    u16x8 bp[4];

    auto load_ab = [&](int k0) {
#pragma unroll
        for (int it = 0; it < 4; ++it) {
            int slot = tid + it * 256, r = slot >> 3, g = (slot & 7) * 8;
            a16p[it] = *(const u16x8*)(A16 + (size_t)(m0 + r) * F_ + k0 + g);
            bp[it]   = *(const u16x8*)(Wt  + (size_t)(n0 + r) * F_ + k0 + g);
        }
    };
    auto write_ab = [&]() {
#pragma unroll
        for (int it = 0; it < 4; ++it) {
            int slot = tid + it * 256, r = slot >> 3, g = (slot & 7) * 8;
            *(u16x8*)&As[r][g] = a16p[it];
            *(u16x8*)&Bs[r][g] = bp[it];
        }
    };

    f32x4 acc[2][8] = {};

    load_ab(0);
    write_ab();
    __syncthreads();
    load_ab(64);

    for (int k0 = 0; k0 < F_; k0 += 64) {
#pragma unroll
        for (int ks = 0; ks < 2; ++ks) {
            f16x8 af[2];
#pragma unroll
            for (int mf = 0; mf < 2; ++mf)
                af[mf] = *(const f16x8*)&As[w * 32 + mf * 16 + lx][ks * 32 + quad * 8];
#pragma unroll
            for (int nt = 0; nt < 8; ++nt) {
                f16x8 bf = *(const f16x8*)&Bs[nt * 16 + lx][ks * 32 + quad * 8];
#pragma unroll
                for (int mf = 0; mf < 2; ++mf)
                    acc[mf][nt] = __builtin_amdgcn_mfma_f32_16x16x32_f16(af[mf], bf, acc[mf][nt], 0, 0, 0);
            }
        }
        if (k0 < F_ - 64) {
            __syncthreads();
            write_ab();
            __syncthreads();
            if (k0 < F_ - 128) load_ab(k0 + 128);
        }
    }

#pragma unroll
    for (int mf = 0; mf < 2; ++mf)
#pragma unroll
        for (int nt = 0; nt < 8; ++nt)
#pragma unroll
            for (int i = 0; i < 4; ++i) {
                int m = m0 + w * 32 + mf * 16 + quad * 4 + i;
                int n = n0 + nt * 16 + lx;
                Cf[(size_t)m * F_ + n] = acc[mf][nt][i];
            }
}

// ---------------------------------------------------------------------------
// MFMA flash attention (R8 structure, 81.2 µs — unchanged; serves as the
// control for this round). BQ=256 (4 waves x 64q), split-K x2, Q in regs,
// P in regs (permlane swap), K/V LDS dbuf, one barrier per kt, prefetch
// after the barrier. R6-R8 lesson: wedged at ~39% MfmaUtil by correlated
// dependency structure; source-level scheduling doesn't move it.
// ---------------------------------------------------------------------------
__global__ __launch_bounds__(256, 2) void flash_mfma(
    const u16* __restrict__ Qg, const u16* __restrict__ Kg,
    const u16* __restrict__ Vtg, u16* __restrict__ On, float* __restrict__ Ls) {
    __shared__ u16 Ks[2][64][72];   // fp16, double-buffered
    __shared__ u16 Vs[2][64][72];   // bf16, V^T tile [d][kcol], double-buffered

    const int tid = threadIdx.x;
    const int w = tid >> 6, lane = tid & 63, lx = lane & 15, quad = lane >> 4;

    // decode: 512 = 8 xcd * (2 head * 2 split * 16 qtile)
    const int x = blockIdx.x;
    const int t = x >> 3;
    const int hh = t >> 5;
    const int s = (t >> 4) & 1;
    const int bh = (x & 7) * 2 + hh;
    const int q0 = (t & 15) * 256;

    const u16* Qp = Qg + ((size_t)bh * L_ + q0) * D_;
    const u16* Kp = Kg + (size_t)bh * L_ * D_ + (size_t)(s * KHALF) * D_;
    const u16* Vp = Vtg + (size_t)bh * D_ * L_ + s * KHALF;

    // Q fragments straight to registers (B-operand layout), 64 q-rows/wave
    f16x8 qreg[4][2];
#pragma unroll
    for (int qf = 0; qf < 4; ++qf)
#pragma unroll
        for (int ks = 0; ks < 2; ++ks)
            qreg[qf][ks] = *(const f16x8*)(Qp + (size_t)(w * 64 + qf * 16 + lx) * D_ +
                                           ks * 32 + quad * 8);

    u16x8 kp[2], vp[2];
    auto load_kv = [&](int kt) {
#pragma unroll
        for (int it = 0; it < 2; ++it) {
            int slot = tid + it * 256, r = slot >> 3, g = (slot & 7) * 8;
            kp[it] = *(const u16x8*)(Kp + (size_t)(kt * 64 + r) * D_ + g);
            vp[it] = *(const u16x8*)(Vp + (size_t)r * L_ + kt * 64 + g);
        }
    };
    auto write_kv = [&](int p) {
#pragma unroll
        for (int it = 0; it < 2; ++it) {
            int slot = tid + it * 256, r = slot >> 3, g = (slot & 7) * 8;
            *(u16x8*)&Ks[p][r][g] = kp[it];
            *(u16x8*)&Vs[p][r][g] = vp[it];
        }
    };

    const bf16x8 vone = {0x3F80, 0x3F80, 0x3F80, 0x3F80,
                         0x3F80, 0x3F80, 0x3F80, 0x3F80};  // bf16 1.0 x8
    f32x4 o[4][4] = {};
    f32x4 osum[4] = {};

    load_kv(0);
    write_kv(0);
    __syncthreads();
    load_kv(1);   // in flight during first compute

    const int NT = KHALF / 64;
    for (int kt = 0; kt < NT; ++kt) {
        const int p = kt & 1;

        // ---- QK (both halves): 32 back-to-back MFMAs ---------------------
        // S^T = K Q^T : lane holds S^T[k=nt*16+quad*4+i][q=w*64+qf*16+lx]
        f32x4 sv[4][4] = {};
#pragma unroll
        for (int ks = 0; ks < 2; ++ks)
#pragma unroll
            for (int nt = 0; nt < 4; ++nt) {
                f16x8 ak = *(const f16x8*)&Ks[p][nt * 16 + lx][ks * 32 + quad * 8];
#pragma unroll
                for (int qf = 0; qf < 4; ++qf)
                    sv[nt][qf] = __builtin_amdgcn_mfma_f32_16x16x32_f16(ak, qreg[qf][ks], sv[nt][qf], 0, 0, 0);
            }

        // stage next tile into the other buffer (regs loaded ≥1 kt ago ->
        // the implicit vmcnt wait here is fully covered by QK)
        if (kt < NT - 1) write_kv(p ^ 1);

        // ---- softmax (both halves), pure VALU — overlaps the other
        //      wave's MFMA blocks; permlane swap keeps P in registers -----
        bf16x8 ap0[4], ap1[4];
#pragma unroll
        for (int half = 0; half < 2; ++half)
#pragma unroll
            for (int qf = 0; qf < 4; ++qf) {
                u32 pu[2], pw[2];
#pragma unroll
                for (int n = 0; n < 2; ++n) {
                    u32 ub[4];
#pragma unroll
                    for (int i = 0; i < 4; ++i)
                        ub[i] = __float_as_uint(__builtin_amdgcn_exp2f(sv[half * 2 + n][qf][i]));
                    pu[n] = __builtin_amdgcn_perm(ub[1], ub[0], 0x07060302u);
                    pw[n] = __builtin_amdgcn_perm(ub[3], ub[2], 0x07060302u);
                }
                u32x2 r  = __builtin_amdgcn_permlane32_swap(pu[0], pu[1], false, false);
                u32x2 r2 = __builtin_amdgcn_permlane16_swap(r[0], r[1], false, false);
                u32x2 tt = __builtin_amdgcn_permlane32_swap(pw[0], pw[1], false, false);
                u32x2 t2 = __builtin_amdgcn_permlane16_swap(tt[0], tt[1], false, false);
                union { u32 d[4]; bf16x8 h; } cvt;
                cvt.d[0] = r2[0];
                cvt.d[1] = t2[0];
                cvt.d[2] = r2[1];
                cvt.d[3] = t2[1];
                if (half == 0) ap0[qf] = cvt.h; else ap1[qf] = cvt.h;
            }

        // ---- PV (both halves): 40 back-to-back MFMAs ---------------------
        __builtin_amdgcn_s_setprio(1);
#pragma unroll
        for (int qf = 0; qf < 4; ++qf)
            osum[qf] = __builtin_amdgcn_mfma_f32_16x16x32_bf16(ap0[qf], vone, osum[qf], 0, 0, 0);
#pragma unroll
        for (int nt = 0; nt < 4; ++nt) {
            bf16x8 bv = *(const bf16x8*)&Vs[p][nt * 16 + lx][quad * 8];
#pragma unroll
            for (int qf = 0; qf < 4; ++qf)
                o[qf][nt] = __builtin_amdgcn_mfma_f32_16x16x32_bf16(ap0[qf], bv, o[qf][nt], 0, 0, 0);
        }
#pragma unroll
        for (int qf = 0; qf < 4; ++qf)
            osum[qf] = __builtin_amdgcn_mfma_f32_16x16x32_bf16(ap1[qf], vone, osum[qf], 0, 0, 0);
#pragma unroll
        for (int nt = 0; nt < 4; ++nt) {
            bf16x8 bv = *(const bf16x8*)&Vs[p][nt * 16 + lx][32 + quad * 8];
#pragma unroll
            for (int qf = 0; qf < 4; ++qf)
                o[qf][nt] = __builtin_amdgcn_mfma_f32_16x16x32_bf16(ap1[qf], bv, o[qf][nt], 0, 0, 0);
        }
        __builtin_amdgcn_s_setprio(0);

        if (kt < NT - 1) __syncthreads();  // drains LDS writes + OLD loads only
        if (kt < NT - 2) load_kv(kt + 2);  // issued AFTER the barrier
    }

    // write On = O/l (fp16, [B,L,H*D]) and l (f32)
    const int b = bh >> 3, h = bh & 7;
    u16* Op = On + (size_t)s * M_ * F_;
#pragma unroll
    for (int qf = 0; qf < 4; ++qf) {
        float linv[4];
#pragma unroll
        for (int i = 0; i < 4; ++i) linv[i] = 1.f / osum[qf][i];
#pragma unroll
        for (int nt = 0; nt < 4; ++nt)
#pragma unroll
            for (int i = 0; i < 4; ++i) {
                int l = q0 + w * 64 + qf * 16 + quad * 4 + i;
                Op[((size_t)b * L_ + l) * (H_ * D_) + h * D_ + nt * 16 + lx] =
                    f2h(o[qf][nt][i] * linv[i]);
            }
        if (lx == 0) {
            float* lp = Ls + ((size_t)s * (B_ * H_) + bh) * L_ +
                        q0 + w * 64 + qf * 16 + quad * 4;
#pragma unroll
            for (int i = 0; i < 4; ++i) lp[i] = osum[qf][i];
        }
    }
}

// ---------------------------------------------------------------------------
// Combine split-K partials: O = (l1*O1n + l2*O2n) / (l1+l2).
// ---------------------------------------------------------------------------
__global__ __launch_bounds__(256) void reduce_kernel(
    const u16* __restrict__ On, const float* __restrict__ Ls,
    u16* __restrict__ Ow) {
    int gid = blockIdx.x * 256 + threadIdx.x;  // u16x8 group, grid covers M_*F_/8
    size_t off = (size_t)gid * 8;
    int row = gid >> 3;                        // 64 elems per (b,l,h) row
    int b = row >> 15, rem = row & 32767;
    int l = rem >> 3, h = rem & 7;
    int lidx = ((b * H_ + h) << 12) + l;
    float l1 = Ls[lidx], l2 = Ls[B_ * H_ * L_ + lidx];
    float w1 = l1 / (l1 + l2), w2 = 1.f - w1;
    u16x8 a = *(const u16x8*)(On + off);
    u16x8 c = *(const u16x8*)(On + (size_t)M_ * F_ + off);
    u16 r[8];
#pragma unroll
    for (int j = 0; j < 8; ++j)
        r[j] = f2h(w1 * h2f(a[j]) + w2 * h2f(c[j]));
    *(u16x8*)(Ow + off) = *(u16x8*)r;
}

// ---------------------------------------------------------------------------
extern "C" void kernel_launch(void* const* d_in, const int* in_sizes, int n_in,
                              void* d_out, int out_size, void* d_ws, size_t ws_size,
                              hipStream_t stream)
{
    const float* Xq  = (const float*)d_in[0];
    const float* Xkv = (const float*)d_in[1];
    const float* Wq  = (const float*)d_in[2];
    const float* Wk  = (const float*)d_in[3];
    const float* Wv  = (const float*)d_in[4];
    const float* Wo  = (const float*)d_in[5];
    float* out = (float*)d_out;

    u16* ws  = (u16*)d_ws;
    const size_t MF = (size_t)M_ * F_;
    const size_t FF = (size_t)F_ * F_;
    u16* Wqt = ws;             // W^T 512x512 fp16 each
    u16* Wkt = Wqt + FF;
    u16* Wvt = Wkt + FF;
    u16* Wot = Wvt + FF;
    u16* Qw  = Wot + FF;       // [B,H,L,D] fp16, pre-scaled by log2e
    u16* Kw  = Qw + MF;        // [B,H,L,D] fp16
    u16* Vw  = Kw + MF;        // [B,H,D,L] bf16
    u16* On  = Vw + MF;        // 2 x [B,L,H*D] fp16 split partials
    float* Ls = (float*)(On + 2 * MF);  // 2 x [BH, L] f32
    u16* Ow  = Qw;             // reduced O aliases Qw (dead after flash)

    wt_kernel<<<dim3(16, 16, 4), 256, 0, stream>>>(Wq, Wk, Wv, Wo,
                                                   Wqt, Wkt, Wvt, Wot);

    proj_kernel<<<dim3(64, 8, 2), 256, 0, stream>>>(Xq, Xkv, Wqt, Wkt, Wvt,
                                                    Qw, Kw, Vw);

    flash_mfma<<<dim3(512), 256, 0, stream>>>(Qw, Kw, Vw, On, Ls);

    reduce_kernel<<<dim3((int)(MF / 8 / 256)), 256, 0, stream>>>(On, Ls, Ow);

    out_gemm<<<dim3(64, 4), 256, 0, stream>>>(Ow, Wot, out);
}

// Round 10
// 198.398 us; speedup vs baseline: 3.0982x; 1.0100x over previous
//
#include <hip/hip_runtime.h>
#include <hip/hip_bf16.h>

typedef short bf16x8 __attribute__((ext_vector_type(8)));
typedef _Float16 f16;
typedef f16 f16x8 __attribute__((ext_vector_type(8)));
typedef float f32x4 __attribute__((ext_vector_type(4)));
typedef unsigned short u16;
typedef u16 u16x8 __attribute__((ext_vector_type(8)));
typedef unsigned int u32;
typedef u32 u32x2 __attribute__((ext_vector_type(2)));

#define B_  2
#define L_  4096
#define F_  512
#define H_  8
#define D_  64
#define M_  8192       // B_*L_
#define NSPL 2         // flash split-K factor
#define KHALF (L_ / NSPL)

#define LOG2E 1.442695041f

__device__ inline u16 f2bf(float f) {
    union { float f; unsigned u; } v; v.f = f;
    unsigned r = v.u + 0x7fff + ((v.u >> 16) & 1);  // RNE
    return (u16)(r >> 16);
}
__device__ inline u16 f2h(float f) {
    union { f16 h; u16 u; } v; v.h = (f16)f;  // RNE hw cvt
    return v.u;
}
__device__ inline float h2f(u16 u) {
    union { u16 u; f16 h; } v; v.u = u;
    return (float)v.h;
}

// ---------------------------------------------------------------------------
// Fused weight transpose: W [512 k][512 n] fp32 -> Wt [512 n][512 k] fp16.
// ---------------------------------------------------------------------------
__global__ __launch_bounds__(256) void wt_kernel(
    const float* __restrict__ Wq, const float* __restrict__ Wk,
    const float* __restrict__ Wv, const float* __restrict__ Wo,
    u16* __restrict__ Tq, u16* __restrict__ Tk,
    u16* __restrict__ Tv, u16* __restrict__ To) {
    __shared__ float t[32][33];
    const int z = blockIdx.z;
    const float* in = (z == 0) ? Wq : (z == 1) ? Wk : (z == 2) ? Wv : Wo;
    u16* out = (z == 0) ? Tq : (z == 1) ? Tk : (z == 2) ? Tv : To;
    int k0 = blockIdx.y * 32, n0 = blockIdx.x * 32;
    int c = threadIdx.x & 31, r8 = threadIdx.x >> 5;
#pragma unroll
    for (int i = 0; i < 4; ++i) {
        int r = r8 * 4 + i;
        t[r][c] = in[(size_t)(k0 + r) * F_ + n0 + c];
    }
    __syncthreads();
#pragma unroll
    for (int i = 0; i < 4; ++i) {
        int r = r8 * 4 + i;
        out[(size_t)(n0 + r) * F_ + k0 + c] = f2h(t[c][r]);
    }
}

// ---------------------------------------------------------------------------
// Projection kernel, R10: one GEMM per block (z=0 Q, z=1 K, z=2 V).
// R9's z=1 blocks did 2 GEMMs (K+V) = 2x the work of z=0 -> load imbalance.
// Now every block is a uniform 128x64x512 GEMM (512 MFMA); V keeps its
// bf16-transpose epilogue. LDS 27.6 KB (was 36.9), regs ~80 (was ~96).
// A re-read +33% but L2-local thanks to the m-major grid (XCD = m%8 owns
// a 2+2 MB A panel reused across all n and z).
// ---------------------------------------------------------------------------
__global__ __launch_bounds__(256, 3) void proj_kernel(
    const float* __restrict__ Xq, const float* __restrict__ Xkv,
    const u16* __restrict__ Wqt, const u16* __restrict__ Wkt,
    const u16* __restrict__ Wvt,
    u16* __restrict__ Qw, u16* __restrict__ Kw, u16* __restrict__ Vw) {
    __shared__ u16 Ah[128][72];
    __shared__ u16 B1[64][72];
    const int tid = threadIdx.x;
    const int w = tid >> 6, lane = tid & 63, lx = lane & 15, quad = lane >> 4;
    const int m0 = blockIdx.x * 128, n0 = blockIdx.y * 64;
    const int z = blockIdx.z;
    const float* A = (z == 0) ? Xq : Xkv;
    const u16* W1 = (z == 0) ? Wqt : (z == 1) ? Wkt : Wvt;

    float4 apre[8];
    u16x8 b1p[2];

    auto load_ab = [&](int k0) {
#pragma unroll
        for (int it = 0; it < 4; ++it) {
            int slot = tid + it * 256, r = slot >> 3, g = (slot & 7) * 8;
            apre[2 * it]     = *(const float4*)(A + (size_t)(m0 + r) * F_ + k0 + g);
            apre[2 * it + 1] = *(const float4*)(A + (size_t)(m0 + r) * F_ + k0 + g + 4);
        }
#pragma unroll
        for (int it = 0; it < 2; ++it) {
            int slot = tid + it * 256, r = slot >> 3, g = (slot & 7) * 8;
            b1p[it] = *(const u16x8*)(W1 + (size_t)(n0 + r) * F_ + k0 + g);
        }
    };
    auto write_ab = [&]() {
#pragma unroll
        for (int it = 0; it < 4; ++it) {
            int slot = tid + it * 256, r = slot >> 3, g = (slot & 7) * 8;
            float4 f0 = apre[2 * it], f1 = apre[2 * it + 1];
            u16 th[8] = {f2h(f0.x), f2h(f0.y), f2h(f0.z), f2h(f0.w),
                         f2h(f1.x), f2h(f1.y), f2h(f1.z), f2h(f1.w)};
            *(u16x8*)&Ah[r][g] = *(u16x8*)th;
        }
#pragma unroll
        for (int it = 0; it < 2; ++it) {
            int slot = tid + it * 256, r = slot >> 3, g = (slot & 7) * 8;
            *(u16x8*)&B1[r][g] = b1p[it];
        }
    };

    f32x4 acc1[2][4] = {};

    load_ab(0);
    write_ab();
    __syncthreads();
    load_ab(64);   // in flight during first compute

    for (int k0 = 0; k0 < F_; k0 += 64) {
#pragma unroll
        for (int ks = 0; ks < 2; ++ks) {
            f16x8 af[2];
#pragma unroll
            for (int mf = 0; mf < 2; ++mf)
                af[mf] = *(const f16x8*)&Ah[w * 32 + mf * 16 + lx][ks * 32 + quad * 8];
#pragma unroll
            for (int nt = 0; nt < 4; ++nt) {
                f16x8 b1 = *(const f16x8*)&B1[nt * 16 + lx][ks * 32 + quad * 8];
#pragma unroll
                for (int mf = 0; mf < 2; ++mf)
                    acc1[mf][nt] = __builtin_amdgcn_mfma_f32_16x16x32_f16(af[mf], b1, acc1[mf][nt], 0, 0, 0);
            }
        }
        if (k0 < F_ - 64) {
            __syncthreads();   // loads for k0+64 landed during this compute
            write_ab();
            __syncthreads();
            if (k0 < F_ - 128) load_ab(k0 + 128);  // issued AFTER barriers
        }
    }

    const int h = n0 >> 6;
    if (z < 2) {
        const float scl = (z == 0) ? LOG2E : 1.0f;
        u16* C1 = (z == 0) ? Qw : Kw;
#pragma unroll
        for (int mf = 0; mf < 2; ++mf)
#pragma unroll
            for (int nt = 0; nt < 4; ++nt)
#pragma unroll
                for (int i = 0; i < 4; ++i) {
                    int m = m0 + w * 32 + mf * 16 + quad * 4 + i;
                    int b = m >> 12, l = m & 4095;
                    int d = nt * 16 + lx;
                    C1[((size_t)(b * H_ + h) * L_ + l) * D_ + d] = f2h(acc1[mf][nt][i] * scl);
                }
    } else {
        // V: bf16 transpose epilogue -> Vw [B,H,D,L]
        __syncthreads();
#pragma unroll
        for (int mf = 0; mf < 2; ++mf)
#pragma unroll
            for (int nt = 0; nt < 4; ++nt)
#pragma unroll
                for (int i = 0; i < 4; ++i)
                    Ah[w * 32 + mf * 16 + quad * 4 + i][nt * 16 + lx] = f2bf(acc1[mf][nt][i]);
        __syncthreads();
        int d = tid >> 2, seg = (tid & 3) * 32;
        int b = m0 >> 12;
        u16 tmp[32];
#pragma unroll
        for (int j = 0; j < 32; ++j) tmp[j] = Ah[seg + j][d];
        size_t base = ((size_t)(b * H_ + h) * D_ + d) * L_ + (m0 & 4095) + seg;
#pragma unroll
        for (int c = 0; c < 4; ++c)
            *(u16x8*)(Vw + base + c * 8) = *(u16x8*)&tmp[c * 8];
    }
}

// ---------------------------------------------------------------------------
// Out-projection GEMM, 128x128 tile, m-major grid (XCD = m%8, L2-local).
// ---------------------------------------------------------------------------
__global__ __launch_bounds__(256) void out_gemm(const u16* __restrict__ A16,
                                                const u16* __restrict__ Wt,
                                                float* __restrict__ Cf) {
    __shared__ u16 As[128][72];
    __shared__ u16 Bs[128][72];
    const int tid = threadIdx.x;
    const int w = tid >> 6, lane = tid & 63, lx = lane & 15, quad = lane >> 4;
    const int m0 = blockIdx.x * 128, n0 = blockIdx.y * 128;

    u16x8 a16p[4];
    u16x8 bp[4];

    auto load_ab = [&](int k0) {
#pragma unroll
        for (int it = 0; it < 4; ++it) {
            int slot = tid + it * 256, r = slot >> 3, g = (slot & 7) * 8;
            a16p[it] = *(const u16x8*)(A16 + (size_t)(m0 + r) * F_ + k0 + g);
            bp[it]   = *(const u16x8*)(Wt  + (size_t)(n0 + r) * F_ + k0 + g);
        }
    };
    auto write_ab = [&]() {
#pragma unroll
        for (int it = 0; it < 4; ++it) {
            int slot = tid + it * 256, r = slot >> 3, g = (slot & 7) * 8;
            *(u16x8*)&As[r][g] = a16p[it];
            *(u16x8*)&Bs[r][g] = bp[it];
        }
    };

    f32x4 acc[2][8] = {};

    load_ab(0);
    write_ab();
    __syncthreads();
    load_ab(64);

    for (int k0 = 0; k0 < F_; k0 += 64) {
#pragma unroll
        for (int ks = 0; ks < 2; ++ks) {
            f16x8 af[2];
#pragma unroll
            for (int mf = 0; mf < 2; ++mf)
                af[mf] = *(const f16x8*)&As[w * 32 + mf * 16 + lx][ks * 32 + quad * 8];
#pragma unroll
            for (int nt = 0; nt < 8; ++nt) {
                f16x8 bf = *(const f16x8*)&Bs[nt * 16 + lx][ks * 32 + quad * 8];
#pragma unroll
                for (int mf = 0; mf < 2; ++mf)
                    acc[mf][nt] = __builtin_amdgcn_mfma_f32_16x16x32_f16(af[mf], bf, acc[mf][nt], 0, 0, 0);
            }
        }
        if (k0 < F_ - 64) {
            __syncthreads();
            write_ab();
            __syncthreads();
            if (k0 < F_ - 128) load_ab(k0 + 128);
        }
    }

#pragma unroll
    for (int mf = 0; mf < 2; ++mf)
#pragma unroll
        for (int nt = 0; nt < 8; ++nt)
#pragma unroll
            for (int i = 0; i < 4; ++i) {
                int m = m0 + w * 32 + mf * 16 + quad * 4 + i;
                int n = n0 + nt * 16 + lx;
                Cf[(size_t)m * F_ + n] = acc[mf][nt][i];
            }
}

// ---------------------------------------------------------------------------
// MFMA flash attention, R10: fine-grained MFMA<->VALU interleave.
// R9 model reframe: VALUBusy excludes MFMA (m98/m114 reading) -> flash is
// at 39% MFMA + 45% VALU = 84% combined; jointly pipe-bound. The residual
// ~16% is in-phase loss (co-resident waves do softmax simultaneously).
// Fix: a single wave's instruction stream alternates the two pipes:
//   QK_A -> [per qf: 4 QK_B MFMAs ; SM_A(qf) VALU] ->
//   [per qf: 5 PV_A MFMAs ; SM_B(qf) VALU] -> PV_B
// so each wave feeds the MFMA pipe during its own softmax regardless of
// partner-wave phase. Operand ds_reads hoisted (akB, bvA/bvB) so the
// interleave is pure MFMA/VALU. Accumulation order per sv/o/osum is
// unchanged -> bit-identical numerics vs R8.
// ---------------------------------------------------------------------------
__global__ __launch_bounds__(256, 2) void flash_mfma(
    const u16* __restrict__ Qg, const u16* __restrict__ Kg,
    const u16* __restrict__ Vtg, u16* __restrict__ On, float* __restrict__ Ls) {
    __shared__ u16 Ks[2][64][72];   // fp16, double-buffered
    __shared__ u16 Vs[2][64][72];   // bf16, V^T tile [d][kcol], double-buffered

    const int tid = threadIdx.x;
    const int w = tid >> 6, lane = tid & 63, lx = lane & 15, quad = lane >> 4;

    // decode: 512 = 8 xcd * (2 head * 2 split * 16 qtile)
    const int x = blockIdx.x;
    const int t = x >> 3;
    const int hh = t >> 5;
    const int s = (t >> 4) & 1;
    const int bh = (x & 7) * 2 + hh;
    const int q0 = (t & 15) * 256;

    const u16* Qp = Qg + ((size_t)bh * L_ + q0) * D_;
    const u16* Kp = Kg + (size_t)bh * L_ * D_ + (size_t)(s * KHALF) * D_;
    const u16* Vp = Vtg + (size_t)bh * D_ * L_ + s * KHALF;

    // Q fragments straight to registers (B-operand layout), 64 q-rows/wave
    f16x8 qreg[4][2];
#pragma unroll
    for (int qf = 0; qf < 4; ++qf)
#pragma unroll
        for (int ks = 0; ks < 2; ++ks)
            qreg[qf][ks] = *(const f16x8*)(Qp + (size_t)(w * 64 + qf * 16 + lx) * D_ +
                                           ks * 32 + quad * 8);

    u16x8 kp[2], vp[2];
    auto load_kv = [&](int kt) {
#pragma unroll
        for (int it = 0; it < 2; ++it) {
            int slot = tid + it * 256, r = slot >> 3, g = (slot & 7) * 8;
            kp[it] = *(const u16x8*)(Kp + (size_t)(kt * 64 + r) * D_ + g);
            vp[it] = *(const u16x8*)(Vp + (size_t)r * L_ + kt * 64 + g);
        }
    };
    auto write_kv = [&](int p) {
#pragma unroll
        for (int it = 0; it < 2; ++it) {
            int slot = tid + it * 256, r = slot >> 3, g = (slot & 7) * 8;
            *(u16x8*)&Ks[p][r][g] = kp[it];
            *(u16x8*)&Vs[p][r][g] = vp[it];
        }
    };

    // softmax of one half for one qf: sv pair -> bf16 A-fragment (permlane)
    auto smqf = [&](const f32x4& s0, const f32x4& s1) -> bf16x8 {
        u32 ub0[4], ub1[4];
#pragma unroll
        for (int i = 0; i < 4; ++i) {
            ub0[i] = __float_as_uint(__builtin_amdgcn_exp2f(s0[i]));
            ub1[i] = __float_as_uint(__builtin_amdgcn_exp2f(s1[i]));
        }
        u32 pu0 = __builtin_amdgcn_perm(ub0[1], ub0[0], 0x07060302u);
        u32 pw0 = __builtin_amdgcn_perm(ub0[3], ub0[2], 0x07060302u);
        u32 pu1 = __builtin_amdgcn_perm(ub1[1], ub1[0], 0x07060302u);
        u32 pw1 = __builtin_amdgcn_perm(ub1[3], ub1[2], 0x07060302u);
        u32x2 r  = __builtin_amdgcn_permlane32_swap(pu0, pu1, false, false);
        u32x2 r2 = __builtin_amdgcn_permlane16_swap(r[0], r[1], false, false);
        u32x2 tt = __builtin_amdgcn_permlane32_swap(pw0, pw1, false, false);
        u32x2 t2 = __builtin_amdgcn_permlane16_swap(tt[0], tt[1], false, false);
        union { u32 d[4]; bf16x8 h; } cvt;
        cvt.d[0] = r2[0];
        cvt.d[1] = t2[0];
        cvt.d[2] = r2[1];
        cvt.d[3] = t2[1];
        return cvt.h;
    };

    const bf16x8 vone = {0x3F80, 0x3F80, 0x3F80, 0x3F80,
                         0x3F80, 0x3F80, 0x3F80, 0x3F80};  // bf16 1.0 x8
    f32x4 o[4][4] = {};
    f32x4 osum[4] = {};

    load_kv(0);
    write_kv(0);
    __syncthreads();
    load_kv(1);   // in flight during first compute

    const int NT = KHALF / 64;
    for (int kt = 0; kt < NT; ++kt) {
        const int p = kt & 1;

        // ---- section 1: QK half A (nt 0,1), 16 MFMAs ---------------------
        // S^T = K Q^T : lane holds S^T[k=nt*16+quad*4+i][q=w*64+qf*16+lx]
        f32x4 sv[4][4] = {};
#pragma unroll
        for (int ks = 0; ks < 2; ++ks)
#pragma unroll
            for (int nt = 0; nt < 2; ++nt) {
                f16x8 ak = *(const f16x8*)&Ks[p][nt * 16 + lx][ks * 32 + quad * 8];
#pragma unroll
                for (int qf = 0; qf < 4; ++qf)
                    sv[nt][qf] = __builtin_amdgcn_mfma_f32_16x16x32_f16(ak, qreg[qf][ks], sv[nt][qf], 0, 0, 0);
            }

        // hoist half-B K fragments (4 ds_reads) for the interleave
        f16x8 akB[2][2];  // [ks][nt-2]
#pragma unroll
        for (int ks = 0; ks < 2; ++ks)
#pragma unroll
            for (int nt = 0; nt < 2; ++nt)
                akB[ks][nt] = *(const f16x8*)&Ks[p][(nt + 2) * 16 + lx][ks * 32 + quad * 8];

        // ---- section 2: per qf {4 QK_B MFMAs ; SM_A(qf) VALU} ------------
        bf16x8 apA[4];
#pragma unroll
        for (int qf = 0; qf < 4; ++qf) {
            sv[2][qf] = __builtin_amdgcn_mfma_f32_16x16x32_f16(akB[0][0], qreg[qf][0], sv[2][qf], 0, 0, 0);
            sv[3][qf] = __builtin_amdgcn_mfma_f32_16x16x32_f16(akB[0][1], qreg[qf][0], sv[3][qf], 0, 0, 0);
            sv[2][qf] = __builtin_amdgcn_mfma_f32_16x16x32_f16(akB[1][0], qreg[qf][1], sv[2][qf], 0, 0, 0);
            sv[3][qf] = __builtin_amdgcn_mfma_f32_16x16x32_f16(akB[1][1], qreg[qf][1], sv[3][qf], 0, 0, 0);
            apA[qf] = smqf(sv[0][qf], sv[1][qf]);   // VALU fills MFMA shadow
        }

        // stage next tile into the other buffer (regs loaded ≥1 kt ago)
        if (kt < NT - 1) write_kv(p ^ 1);

        // hoist V fragments for half A (ds_reads)
        bf16x8 bvA[4];
#pragma unroll
        for (int nt = 0; nt < 4; ++nt)
            bvA[nt] = *(const bf16x8*)&Vs[p][nt * 16 + lx][quad * 8];

        // ---- section 3: per qf {5 PV_A MFMAs ; SM_B(qf) VALU} ------------
        __builtin_amdgcn_s_setprio(1);
        bf16x8 apB[4];
#pragma unroll
        for (int qf = 0; qf < 4; ++qf) {
            osum[qf] = __builtin_amdgcn_mfma_f32_16x16x32_bf16(apA[qf], vone, osum[qf], 0, 0, 0);
#pragma unroll
            for (int nt = 0; nt < 4; ++nt)
                o[qf][nt] = __builtin_amdgcn_mfma_f32_16x16x32_bf16(apA[qf], bvA[nt], o[qf][nt], 0, 0, 0);
            apB[qf] = smqf(sv[2][qf], sv[3][qf]);   // VALU fills MFMA shadow
        }

        // ---- section 4: PV half B, 20 MFMAs ------------------------------
        bf16x8 bvB[4];
#pragma unroll
        for (int nt = 0; nt < 4; ++nt)
            bvB[nt] = *(const bf16x8*)&Vs[p][nt * 16 + lx][32 + quad * 8];
#pragma unroll
        for (int qf = 0; qf < 4; ++qf)
            osum[qf] = __builtin_amdgcn_mfma_f32_16x16x32_bf16(apB[qf], vone, osum[qf], 0, 0, 0);
#pragma unroll
        for (int nt = 0; nt < 4; ++nt) {
#pragma unroll
            for (int qf = 0; qf < 4; ++qf)
                o[qf][nt] = __builtin_amdgcn_mfma_f32_16x16x32_bf16(apB[qf], bvB[nt], o[qf][nt], 0, 0, 0);
        }
        __builtin_amdgcn_s_setprio(0);

        if (kt < NT - 1) __syncthreads();  // drains LDS writes + OLD loads only
        if (kt < NT - 2) load_kv(kt + 2);  // issued AFTER the barrier
    }

    // write On = O/l (fp16, [B,L,H*D]) and l (f32)
    const int b = bh >> 3, h = bh & 7;
    u16* Op = On + (size_t)s * M_ * F_;
#pragma unroll
    for (int qf = 0; qf < 4; ++qf) {
        float linv[4];
#pragma unroll
        for (int i = 0; i < 4; ++i) linv[i] = 1.f / osum[qf][i];
#pragma unroll
        for (int nt = 0; nt < 4; ++nt)
#pragma unroll
            for (int i = 0; i < 4; ++i) {
                int l = q0 + w * 64 + qf * 16 + quad * 4 + i;
                Op[((size_t)b * L_ + l) * (H_ * D_) + h * D_ + nt * 16 + lx] =
                    f2h(o[qf][nt][i] * linv[i]);
            }
        if (lx == 0) {
            float* lp = Ls + ((size_t)s * (B_ * H_) + bh) * L_ +
                        q0 + w * 64 + qf * 16 + quad * 4;
#pragma unroll
            for (int i = 0; i < 4; ++i) lp[i] = osum[qf][i];
        }
    }
}

// ---------------------------------------------------------------------------
// Combine split-K partials: O = (l1*O1n + l2*O2n) / (l1+l2).
// ---------------------------------------------------------------------------
__global__ __launch_bounds__(256) void reduce_kernel(
    const u16* __restrict__ On, const float* __restrict__ Ls,
    u16* __restrict__ Ow) {
    int gid = blockIdx.x * 256 + threadIdx.x;  // u16x8 group, grid covers M_*F_/8
    size_t off = (size_t)gid * 8;
    int row = gid >> 3;                        // 64 elems per (b,l,h) row
    int b = row >> 15, rem = row & 32767;
    int l = rem >> 3, h = rem & 7;
    int lidx = ((b * H_ + h) << 12) + l;
    float l1 = Ls[lidx], l2 = Ls[B_ * H_ * L_ + lidx];
    float w1 = l1 / (l1 + l2), w2 = 1.f - w1;
    u16x8 a = *(const u16x8*)(On + off);
    u16x8 c = *(const u16x8*)(On + (size_t)M_ * F_ + off);
    u16 r[8];
#pragma unroll
    for (int j = 0; j < 8; ++j)
        r[j] = f2h(w1 * h2f(a[j]) + w2 * h2f(c[j]));
    *(u16x8*)(Ow + off) = *(u16x8*)r;
}

// ---------------------------------------------------------------------------
extern "C" void kernel_launch(void* const* d_in, const int* in_sizes, int n_in,
                              void* d_out, int out_size, void* d_ws, size_t ws_size,
                              hipStream_t stream)
{
    const float* Xq  = (const float*)d_in[0];
    const float* Xkv = (const float*)d_in[1];
    const float* Wq  = (const float*)d_in[2];
    const float* Wk  = (const float*)d_in[3];
    const float* Wv  = (const float*)d_in[4];
    const float* Wo  = (const float*)d_in[5];
    float* out = (float*)d_out;

    u16* ws  = (u16*)d_ws;
    const size_t MF = (size_t)M_ * F_;
    const size_t FF = (size_t)F_ * F_;
    u16* Wqt = ws;             // W^T 512x512 fp16 each
    u16* Wkt = Wqt + FF;
    u16* Wvt = Wkt + FF;
    u16* Wot = Wvt + FF;
    u16* Qw  = Wot + FF;       // [B,H,L,D] fp16, pre-scaled by log2e
    u16* Kw  = Qw + MF;        // [B,H,L,D] fp16
    u16* Vw  = Kw + MF;        // [B,H,D,L] bf16
    u16* On  = Vw + MF;        // 2 x [B,L,H*D] fp16 split partials
    float* Ls = (float*)(On + 2 * MF);  // 2 x [BH, L] f32
    u16* Ow  = Qw;             // reduced O aliases Qw (dead after flash)

    wt_kernel<<<dim3(16, 16, 4), 256, 0, stream>>>(Wq, Wk, Wv, Wo,
                                                   Wqt, Wkt, Wvt, Wot);

    proj_kernel<<<dim3(64, 8, 3), 256, 0, stream>>>(Xq, Xkv, Wqt, Wkt, Wvt,
                                                    Qw, Kw, Vw);

    flash_mfma<<<dim3(512), 256, 0, stream>>>(Qw, Kw, Vw, On, Ls);

    reduce_kernel<<<dim3((int)(MF / 8 / 256)), 256, 0, stream>>>(On, Ls, Ow);

    out_gemm<<<dim3(64, 4), 256, 0, stream>>>(Ow, Wot, out);
}